// Round 8
// baseline (402.829 us; speedup 1.0000x reference)
//
#include <hip/hip_runtime.h>
#include <hip/hip_bf16.h>

typedef __bf16 bf16;
typedef __bf16 bf16x4 __attribute__((ext_vector_type(4)));
typedef __bf16 bf16x8 __attribute__((ext_vector_type(8)));
typedef float floatx4 __attribute__((ext_vector_type(4)));

#define Bb   2
#define Ss   2048
#define HID  2048
#define NH   16
#define HD   128
#define HG   8

typedef __attribute__((address_space(3))) unsigned int lds_u32;
typedef const __attribute__((address_space(1))) unsigned int gbl_u32;

__device__ __forceinline__ float b2f(bf16 h) {
    unsigned short u = __builtin_bit_cast(unsigned short, h);
    unsigned int x = ((unsigned int)u) << 16;
    return __builtin_bit_cast(float, x);
}
__device__ __forceinline__ bf16 f2b(float f) {
    __hip_bfloat16 t = __float2bfloat16(f);
    return __builtin_bit_cast(bf16, t);
}
__device__ __forceinline__ bf16x8 load8_f32(const float* p) {
    float4 u = *(const float4*)p;
    float4 v = *(const float4*)(p + 4);
    bf16x8 r;
    r[0] = f2b(u.x); r[1] = f2b(u.y); r[2] = f2b(u.z); r[3] = f2b(u.w);
    r[4] = f2b(v.x); r[5] = f2b(v.y); r[6] = f2b(v.z); r[7] = f2b(v.w);
    return r;
}
// async global->LDS, 16B per lane; lds base must be wave-uniform
__device__ __forceinline__ void stage16(const bf16* g, bf16* l) {
    __builtin_amdgcn_global_load_lds((gbl_u32*)g, (lds_u32*)l, 16, 0, 0);
}

// ===========================================================================
// PATH A kernels (ws >= 64 MiB)
// ===========================================================================

// merged f32->bf16 conversion for x (2.10M f4), w_qkv (3.15M f4), w_o (1.05M f4)
__global__ __launch_bounds__(256) void cvt_all(
    const float* __restrict__ x, const float* __restrict__ wq,
    const float* __restrict__ wo,
    bf16* __restrict__ xb, bf16* __restrict__ wqb, bf16* __restrict__ wob)
{
    int idx = blockIdx.x * 256 + threadIdx.x;
    int stride = gridDim.x * 256;
    for (int i = idx; i < 6291456; i += stride) {
        const float* in; bf16* out; int k;
        if (i < 2097152)      { in = x;  out = xb;  k = i; }
        else if (i < 5242880) { in = wq; out = wqb; k = i - 2097152; }
        else                  { in = wo; out = wob; k = i - 5242880; }
        float4 v = ((const float4*)in)[k];
        bf16x4 o; o[0] = f2b(v.x); o[1] = f2b(v.y); o[2] = f2b(v.z); o[3] = f2b(v.w);
        ((bf16x4*)out)[k] = o;
    }
}

// ---------------------------------------------------------------------------
// Single-dispatch QKV GEMM (m97-style LDS staging) + RoPE + head-split.
// (unchanged from r6 — at the 2-phase structural ceiling, 773 TF)
// ---------------------------------------------------------------------------
__global__ __launch_bounds__(256) void qkv_gemm_rope(
    const bf16* __restrict__ xb, const bf16* __restrict__ wqb,
    const float* __restrict__ c0, const float* __restrict__ c1,
    bf16* __restrict__ q, bf16* __restrict__ k, bf16* __restrict__ vT)
{
    __shared__ __attribute__((aligned(16))) char smem[128 * 132 * 2];
    bf16* As = (bf16*)smem;                 // [128*32] = 8 KB (K-loop only)
    bf16* Bs = (bf16*)(smem + 8192);        // [128*32] = 8 KB (K-loop only)
    typedef bf16 (*tile_t)[132];
    tile_t tile = (tile_t)smem;             // [128][132] (epilogue only)

    bool c0cos = (c0[0] > 0.5f);
    const float* cosT = c0cos ? c0 : c1;
    const float* sinT = c0cos ? c1 : c0;

    int tid = threadIdx.x, lane = tid & 63, w = tid >> 6;
    int l15 = lane & 15, quad = lane >> 4;
    int m0 = blockIdx.x * 128, n0 = blockIdx.y * 128;
    int mw = (w >> 1) * 64, nw = (w & 1) * 64;

    int srow = w * 32 + (lane >> 2);
    int scol = (lane & 3) * 8;
    const bf16* ga = xb  + (size_t)(m0 + srow) * HID + scol;
    const bf16* gb = wqb + (size_t)(n0 + srow) * HID + scol;
    bf16* la = As + w * 1024;
    bf16* lb = Bs + w * 1024;

    floatx4 acc[4][4] = {};
    for (int k0 = 0; k0 < HID; k0 += 32) {
        stage16(ga + k0,                    la);
        stage16(ga + (size_t)16 * HID + k0, la + 512);
        stage16(gb + k0,                    lb);
        stage16(gb + (size_t)16 * HID + k0, lb + 512);
        __syncthreads();
        bf16x8 a[4], b[4];
#pragma unroll
        for (int i = 0; i < 4; i++) {
            a[i] = *(const bf16x8*)&As[(mw + i * 16 + l15) * 32 + quad * 8];
            b[i] = *(const bf16x8*)&Bs[(nw + i * 16 + l15) * 32 + quad * 8];
        }
#pragma unroll
        for (int i = 0; i < 4; i++)
#pragma unroll
            for (int j = 0; j < 4; j++)
                acc[i][j] = __builtin_amdgcn_mfma_f32_16x16x32_bf16(a[i], b[j], acc[i][j], 0, 0, 0);
        __syncthreads();
    }
    // after the final __syncthreads above: no As/Bs readers remain, all DMAs
    // drained -> safe to overlay tile on the same LDS.

#pragma unroll
    for (int i = 0; i < 4; i++)
#pragma unroll
        for (int j = 0; j < 4; j++) {
            int row_l = mw + i * 16 + quad * 4;
            int col_l = nw + j * 16 + l15;
#pragma unroll
            for (int r = 0; r < 4; r++)
                tile[row_l + r][col_l] = f2b(acc[i][j][r]);
        }
    __syncthreads();

    int sec = blockIdx.y >> 4;
    int h   = blockIdx.y & 15;
    int bi  = m0 >> 11;
    int bh  = bi * NH + h;
    int sbase = m0 & (Ss - 1);

    if (sec == 2) {
        int d  = tid >> 1;
        int sh = (tid & 1) * 64;
        bf16* vrow = vT + ((size_t)bh * HD + d) * Ss + sbase + sh;
#pragma unroll 4
        for (int i = 0; i < 64; i += 4) {
            bf16x4 pk;
#pragma unroll
            for (int r = 0; r < 4; r++) pk[r] = tile[sh + i + r][d];
            *(bf16x4*)(vrow + i) = pk;
        }
    } else {
        bf16* dst = (sec == 0) ? q : k;
        int d  = tid & 63;
        int r0 = tid >> 6;
#pragma unroll 4
        for (int it = 0; it < 32; it++) {
            int row_l = it * 4 + r0;
            int s = sbase + row_l;
            float x1 = b2f(tile[row_l][d]);
            float x2 = b2f(tile[row_l][d + 64]);
            float cc1 = cosT[s * HD + d];
            float ss1 = sinT[s * HD + d];
            float cc2 = cosT[s * HD + d + 64];
            float ss2 = sinT[s * HD + d + 64];
            size_t o = ((size_t)bh * Ss + s) * HD + d;
            dst[o]      = f2b(x1 * cc1 - x2 * ss1);
            dst[o + 64] = f2b(x2 * cc2 + x1 * ss2);
        }
    }
}

// ---------------------------------------------------------------------------
// Full-grid causal flash attention, v7: 32 queries per wave.
//  attn's dominant cost is LDS-pipe traffic (4 waves x 16KB read + 16KB DMA
//  per block-step ~= 52us/CU). Each wave now serves TWO 16-query groups from
//  the same K/V fragments -> LDS bytes per (q,k) pair halved, barrier count
//  halved. Block = 128 queries; grid = 32 bh x 16 qt = 512 blocks (all
//  resident, 2/CU). qt mapping pairs qt=15-k with qt=k per CU (constant 68
//  steps). Sync structure identical to r4 (stage next / compute cur / bar).
// ---------------------------------------------------------------------------
#define ATTN_C1 (0.08838834764831845f * 1.44269504f)   /* scale * log2(e) */

#define STAGE_KV(BUF, KB)                                                        \
{                                                                                \
    const char* kg = kgbase + (size_t)(KB) * 256;                                \
    const char* vg = vgbase + (size_t)(KB) * 2;                                  \
    _Pragma("unroll")                                                            \
    for (int i = 0; i < 2; i++) {                                                \
        int P  = P0 + i * 1024;                                                  \
        int r  = P >> 8;                                                         \
        int cK = (P & 255) ^ ((r & 7) << 4);                                     \
        stage16((const bf16*)(kg + r * 256 + cK),                                \
                (bf16*)((char*)Kls[BUF] + wave * 2048 + i * 1024));              \
        int d  = P >> 6;                                                         \
        int cV = (P & 63) ^ (((d >> 1) & 3) << 4);                               \
        stage16((const bf16*)(vg + (size_t)d * 4096 + cV),                       \
                (bf16*)((char*)Vls[BUF] + wave * 2048 + i * 1024));              \
    }                                                                            \
}

__global__ __launch_bounds__(256, 2) void attn_full(
    const bf16* __restrict__ Q, const bf16* __restrict__ Kb, const bf16* __restrict__ VT,
    bf16* __restrict__ O)
{
    __shared__ __attribute__((aligned(16))) bf16 Kls[2][32 * 128];
    __shared__ __attribute__((aligned(16))) bf16 Vls[2][128 * 32];
    __shared__ bf16 pls[4][2][16][40];

    // XCD swizzle + balanced qt pairing: id<256 -> qt=15-(id>>5) (big),
    // id>=256 -> qt=(id>>5)-8 (small). CU hosting ids {c, c+256} gets
    // qt pair (15-k, k) -> constant 68 steps. Bijective over (bh, qt).
    int id   = blockIdx.x;
    int xcd  = id & 7;
    int j    = id >> 3;
    int bh   = (xcd << 2) | (j & 3);
    int qt   = (id < 256) ? (15 - (id >> 5)) : ((id >> 5) - 8);

    int tid  = threadIdx.x;
    int wave = tid >> 6;
    int lane = tid & 63;
    int l15  = lane & 15;
    int quad = lane >> 4;

    int q0 = qt * 128 + wave * 32;   // 32-aligned: exactly one masked step
    int qg = q0 + l15;               // group0 row; group1 = qg + 16

    const char* kgbase = (const char*)(Kb + (size_t)bh * Ss * HD);
    const char* vgbase = (const char*)(VT + (size_t)bh * HD * Ss);
    int P0 = wave * 2048 + lane * 16;

    // stage tile 0 into buf 0 ASAP
    STAGE_KV(0, 0);

    const bf16* qptr = Q + ((size_t)bh * Ss + qg) * HD + quad * 8;
    bf16x8 qf0[4], qf1[4];
#pragma unroll
    for (int s = 0; s < 4; s++) {
        qf0[s] = *(const bf16x8*)(qptr + s * 32);
        qf1[s] = *(const bf16x8*)(qptr + (size_t)16 * HD + s * 32);
    }

    float m0v = -1e30f, m1v = -1e30f;
    float bm0 = 1.44269504e30f, bm1 = 1.44269504e30f;
    float ls0 = 0.0f, ls1 = 0.0f;
    floatx4 ctx0[8] = {}, ctx1[8] = {};

    int nsteps = 4 * qt + 4;       // block-uniform
    int buf = 0;
    __syncthreads();               // tile 0 ready (syncthreads drains vmcnt)

    for (int st = 0; st < nsteps; st++) {
        int kb = st * 32;
        if (st + 1 < nsteps) {
            STAGE_KV(buf ^ 1, kb + 32);
        }
        if (kb <= q0) {            // kb,q0 both 32-aligned
            bool masked = (kb == q0);   // wave-uniform, exactly once
            const char* kls = (const char*)Kls[buf];
            const char* vls = (const char*)Vls[buf];

            floatx4 s0 = {0.f,0.f,0.f,0.f}, s1 = {0.f,0.f,0.f,0.f};
            floatx4 s2 = {0.f,0.f,0.f,0.f}, s3 = {0.f,0.f,0.f,0.f};
            __builtin_amdgcn_s_setprio(1);
#pragma unroll
            for (int s = 0; s < 4; s++) {
                int c = (quad * 16 + s * 64) ^ ((l15 & 7) << 4);
                bf16x8 k0 = *(const bf16x8*)(kls + l15 * 256 + c);
                bf16x8 k1 = *(const bf16x8*)(kls + (l15 + 16) * 256 + c);
                s0 = __builtin_amdgcn_mfma_f32_16x16x32_bf16(k0, qf0[s], s0, 0, 0, 0);
                s1 = __builtin_amdgcn_mfma_f32_16x16x32_bf16(k1, qf0[s], s1, 0, 0, 0);
                s2 = __builtin_amdgcn_mfma_f32_16x16x32_bf16(k0, qf1[s], s2, 0, 0, 0);
                s3 = __builtin_amdgcn_mfma_f32_16x16x32_bf16(k1, qf1[s], s3, 0, 0, 0);
            }
            __builtin_amdgcn_s_setprio(0);

            float v00[4], v01[4], v10[4], v11[4];
#pragma unroll
            for (int r = 0; r < 4; r++) {
                int key0 = kb + quad * 4 + r;
                v00[r] = (masked && key0 > qg)           ? -1e9f : s0[r];
                v01[r] = (masked && key0 + 16 > qg)      ? -1e9f : s1[r];
                v10[r] = (masked && key0 > qg + 16)      ? -1e9f : s2[r];
                v11[r] = (masked && key0 + 16 > qg + 16) ? -1e9f : s3[r];
            }
            // per-lane local max -> wave-uniform defer check (no shuffles)
            float lmax0 = fmaxf(fmaxf(fmaxf(v00[0], v00[1]), fmaxf(v00[2], v00[3])),
                                fmaxf(fmaxf(v01[0], v01[1]), fmaxf(v01[2], v01[3])));
            float lmax1 = fmaxf(fmaxf(fmaxf(v10[0], v10[1]), fmaxf(v10[2], v10[3])),
                                fmaxf(fmaxf(v11[0], v11[1]), fmaxf(v11[2], v11[3])));
            bool ok = (lmax0 * 0.08838834764831845f <= m0v + 8.0f) &&
                      (lmax1 * 0.08838834764831845f <= m1v + 8.0f);
            if (!__all(ok)) {
                float tm0 = lmax0, tm1 = lmax1;
                tm0 = fmaxf(tm0, __shfl_xor(tm0, 16));
                tm0 = fmaxf(tm0, __shfl_xor(tm0, 32));
                tm1 = fmaxf(tm1, __shfl_xor(tm1, 16));
                tm1 = fmaxf(tm1, __shfl_xor(tm1, 32));
                float mnew0 = fmaxf(m0v, tm0 * 0.08838834764831845f);
                float mnew1 = fmaxf(m1v, tm1 * 0.08838834764831845f);
                float bmn0 = -mnew0 * 1.44269504f;
                float bmn1 = -mnew1 * 1.44269504f;
                float a0 = __builtin_exp2f(bmn0 - bm0);
                float a1 = __builtin_exp2f(bmn1 - bm1);
                m0v = mnew0; bm0 = bmn0; ls0 *= a0;
                m1v = mnew1; bm1 = bmn1; ls1 *= a1;
#pragma unroll
                for (int t = 0; t < 8; t++) {
                    ctx0[t][0] *= a0; ctx0[t][1] *= a0;
                    ctx0[t][2] *= a0; ctx0[t][3] *= a0;
                    ctx1[t][0] *= a1; ctx1[t][1] *= a1;
                    ctx1[t][2] *= a1; ctx1[t][3] *= a1;
                }
            }
            bf16x4 pk00, pk01, pk10, pk11;
            float ts0 = 0.f, ts1 = 0.f;
#pragma unroll
            for (int r = 0; r < 4; r++) {
                float pe00 = __builtin_exp2f(__builtin_fmaf(v00[r], ATTN_C1, bm0));
                float pe01 = __builtin_exp2f(__builtin_fmaf(v01[r], ATTN_C1, bm0));
                float pe10 = __builtin_exp2f(__builtin_fmaf(v10[r], ATTN_C1, bm1));
                float pe11 = __builtin_exp2f(__builtin_fmaf(v11[r], ATTN_C1, bm1));
                ts0 += pe00 + pe01;
                ts1 += pe10 + pe11;
                pk00[r] = f2b(pe00); pk01[r] = f2b(pe01);
                pk10[r] = f2b(pe10); pk11[r] = f2b(pe11);
            }
            ls0 += ts0;
            ls1 += ts1;
            *(bf16x4*)&pls[wave][0][l15][quad * 4]      = pk00;
            *(bf16x4*)&pls[wave][0][l15][16 + quad * 4] = pk01;
            *(bf16x4*)&pls[wave][1][l15][quad * 4]      = pk10;
            *(bf16x4*)&pls[wave][1][l15][16 + quad * 4] = pk11;
            bf16x8 pf0 = *(const bf16x8*)&pls[wave][0][l15][quad * 8];
            bf16x8 pf1 = *(const bf16x8*)&pls[wave][1][l15][quad * 8];

            __builtin_amdgcn_s_setprio(1);
#pragma unroll
            for (int t = 0; t < 8; t++) {
                int row = t * 16 + l15;
                bf16x8 vf = *(const bf16x8*)(vls + row * 64 +
                                             ((quad * 16) ^ (((row >> 1) & 3) << 4)));
                ctx0[t] = __builtin_amdgcn_mfma_f32_16x16x32_bf16(vf, pf0, ctx0[t], 0, 0, 0);
                ctx1[t] = __builtin_amdgcn_mfma_f32_16x16x32_bf16(vf, pf1, ctx1[t], 0, 0, 0);
            }
            __builtin_amdgcn_s_setprio(0);
        }
        __syncthreads();           // staged tile complete + all reads of buf done
        buf ^= 1;
    }

    // epilogue: cross-lane l reductions (once)
    ls0 += __shfl_xor(ls0, 16);
    ls0 += __shfl_xor(ls0, 32);
    ls1 += __shfl_xor(ls1, 16);
    ls1 += __shfl_xor(ls1, 32);
    float inv0 = 1.0f / ls0;
    float inv1 = 1.0f / ls1;

    int bi = bh >> 4, h = bh & (NH - 1);
    bf16* op0 = O + ((size_t)(bi * Ss + qg)) * HID + h * HD;
    bf16* op1 = op0 + (size_t)16 * HID;
#pragma unroll
    for (int t = 0; t < 8; t++) {
        bf16x4 ov0, ov1;
#pragma unroll
        for (int r = 0; r < 4; r++) {
            ov0[r] = f2b(ctx0[t][r] * inv0);
            ov1[r] = f2b(ctx1[t][r] * inv1);
        }
        *(bf16x4*)(op0 + t * 16 + quad * 4) = ov0;
        *(bf16x4*)(op1 + t * 16 + quad * 4) = ov1;
    }
}

// ---------------------------------------------------------------------------
// Out-projection (r6 version, 128x128 — r7's 64x128 retile regressed)
// ---------------------------------------------------------------------------
__global__ __launch_bounds__(256) void out_gemm(
    const bf16* __restrict__ A, const bf16* __restrict__ B, float* __restrict__ C)
{
    __shared__ bf16 As[128 * 32];
    __shared__ bf16 Bs[128 * 32];

    int tid = threadIdx.x, lane = tid & 63, w = tid >> 6;
    int l15 = lane & 15, quad = lane >> 4;
    int m0 = blockIdx.x * 128, n0 = blockIdx.y * 128;
    int mw = (w >> 1) * 64, nw = (w & 1) * 64;

    int srow = w * 32 + (lane >> 2);
    int scol = (lane & 3) * 8;
    const bf16* ga = A + (size_t)(m0 + srow) * HID + scol;
    const bf16* gb = B + (size_t)(n0 + srow) * HID + scol;
    bf16* la = As + w * 1024;
    bf16* lb = Bs + w * 1024;

    floatx4 acc[4][4] = {};
    for (int k0 = 0; k0 < HID; k0 += 32) {
        stage16(ga + k0,                    la);
        stage16(ga + (size_t)16 * HID + k0, la + 512);
        stage16(gb + k0,                    lb);
        stage16(gb + (size_t)16 * HID + k0, lb + 512);
        __syncthreads();
        bf16x8 a[4], b[4];
#pragma unroll
        for (int i = 0; i < 4; i++) {
            a[i] = *(const bf16x8*)&As[(mw + i * 16 + l15) * 32 + quad * 8];
            b[i] = *(const bf16x8*)&Bs[(nw + i * 16 + l15) * 32 + quad * 8];
        }
#pragma unroll
        for (int i = 0; i < 4; i++)
#pragma unroll
            for (int j = 0; j < 4; j++)
                acc[i][j] = __builtin_amdgcn_mfma_f32_16x16x32_bf16(a[i], b[j], acc[i][j], 0, 0, 0);
        __syncthreads();
    }

#pragma unroll
    for (int i = 0; i < 4; i++)
#pragma unroll
        for (int j = 0; j < 4; j++) {
            int row = m0 + mw + i * 16 + quad * 4;
            int col = n0 + nw + j * 16 + l15;
#pragma unroll
            for (int r = 0; r < 4; r++)
                C[(size_t)(row + r) * HID + col] = acc[i][j][r];
        }
}

// ===========================================================================
// PATH B kernels (round-8 fallback, ws < 64 MiB) — proven passing
// ===========================================================================

__global__ __launch_bounds__(256) void qkv_rope_pass(
    const float* __restrict__ xb, const float* __restrict__ W,
    const float* __restrict__ c0, const float* __restrict__ c1,
    bf16* __restrict__ qc, bf16* __restrict__ kc, bf16* __restrict__ vc, int hg)
{
    __shared__ bf16 tile[128][132];
    bool c0cos = (c0[0] > 0.5f);
    const float* cosT = c0cos ? c0 : c1;
    const float* sinT = c0cos ? c1 : c0;

    int tid = threadIdx.x, lane = tid & 63, wave = tid >> 6;
    int l15 = lane & 15, quad = lane >> 4;
    int sec = blockIdx.y >> 3, hl = blockIdx.y & 7;
    int nbase = sec * (NH * HD) + (hg * HG + hl) * HD;
    int m0 = blockIdx.x * 128 + (wave >> 1) * 64;
    int n0l = (wave & 1) * 64;

    floatx4 acc[4][4] = {};
    const float* ap = xb + (size_t)(m0 + l15) * HID + quad * 8;
    const float* bp = W  + (size_t)(nbase + n0l + l15) * HID + quad * 8;
    for (int k0 = 0; k0 < HID; k0 += 32) {
        bf16x8 a[4], b[4];
#pragma unroll
        for (int i = 0; i < 4; i++) {
            a[i] = load8_f32(ap + (size_t)i * 16 * HID + k0);
            b[i] = load8_f32(bp + (size_t)i * 16 * HID + k0);
        }
#pragma unroll
        for (int i = 0; i < 4; i++)
#pragma unroll
            for (int j = 0; j < 4; j++)
                acc[i][j] = __builtin_amdgcn_mfma_f32_16x16x32_bf16(a[i], b[j], acc[i][j], 0, 0, 0);
    }
    int lr = (wave >> 1) * 64;
#pragma unroll
    for (int i = 0; i < 4; i++)
#pragma unroll
        for (int j = 0; j < 4; j++) {
            int row_l = lr + i * 16 + quad * 4;
            int col_l = n0l + j * 16 + l15;
#pragma unroll
            for (int r = 0; r < 4; r++)
                tile[row_l + r][col_l] = f2b(acc[i][j][r]);
        }
    __syncthreads();

    bf16* dst = (sec == 0) ? qc : (sec == 1) ? kc : vc;
    int d = tid & 63, r0 = tid >> 6;
#pragma unroll 4
    for (int it = 0; it < 32; it++) {
        int row_l = it * 4 + r0;
        int s = blockIdx.x * 128 + row_l;
        float x1 = b2f(tile[row_l][d]);
        float x2 = b2f(tile[row_l][d + 64]);
        size_t o = ((size_t)hl * Ss + s) * HD + d;
        if (sec == 2) { dst[o] = f2b(x1); dst[o + 64] = f2b(x2); }
        else {
            float cc1 = cosT[s * HD + d], ss1 = sinT[s * HD + d];
            float cc2 = cosT[s * HD + d + 64], ss2 = sinT[s * HD + d + 64];
            dst[o]      = f2b(x1 * cc1 - x2 * ss1);
            dst[o + 64] = f2b(x2 * cc2 + x1 * ss2);
        }
    }
}

__global__ __launch_bounds__(256) void attn_pass(
    const bf16* __restrict__ Q, const bf16* __restrict__ Kb, const bf16* __restrict__ Vb,
    bf16* __restrict__ Obase)
{
    __shared__ bf16 pls[4][16][40];
    int hl = blockIdx.x;
    int qt = (gridDim.y - 1) - blockIdx.y;
    int tid = threadIdx.x, wave = tid >> 6, lane = tid & 63;
    int l15 = lane & 15, quad = lane >> 4;
    int q0 = qt * 64 + wave * 16;
    int qg = q0 + l15;

    const bf16* qptr = Q + ((size_t)hl * Ss + qg) * HD + quad * 8;
    bf16x8 qf[4];
#pragma unroll
    for (int s = 0; s < 4; s++) qf[s] = *(const bf16x8*)(qptr + s * 32);

    float m = -1e30f, l = 0.0f;
    floatx4 ctx[8] = {};
    const float scale = 0.08838834764831845f;

    for (int kb = 0; kb <= q0 + 15; kb += 32) {
        floatx4 s0 = {0.f,0.f,0.f,0.f}, s1 = {0.f,0.f,0.f,0.f};
        const bf16* kp0 = Kb + ((size_t)hl * Ss + kb + l15) * HD + quad * 8;
        const bf16* kp1 = kp0 + (size_t)16 * HD;
#pragma unroll
        for (int s = 0; s < 4; s++) {
            bf16x8 k0 = *(const bf16x8*)(kp0 + s * 32);
            bf16x8 k1 = *(const bf16x8*)(kp1 + s * 32);
            s0 = __builtin_amdgcn_mfma_f32_16x16x32_bf16(k0, qf[s], s0, 0, 0, 0);
            s1 = __builtin_amdgcn_mfma_f32_16x16x32_bf16(k1, qf[s], s1, 0, 0, 0);
        }
        float v0[4], v1[4];
#pragma unroll
        for (int r = 0; r < 4; r++) {
            int key0 = kb + quad * 4 + r;
            v0[r] = (key0 > qg)      ? -1e9f : s0[r] * scale;
            v1[r] = (key0 + 16 > qg) ? -1e9f : s1[r] * scale;
        }
        float tmax = fmaxf(fmaxf(fmaxf(v0[0], v0[1]), fmaxf(v0[2], v0[3])),
                           fmaxf(fmaxf(v1[0], v1[1]), fmaxf(v1[2], v1[3])));
        tmax = fmaxf(tmax, __shfl_xor(tmax, 16));
        tmax = fmaxf(tmax, __shfl_xor(tmax, 32));
        float mnew = fmaxf(m, tmax);
        float alpha = __expf(m - mnew);
        float p0[4], p1[4], tsum = 0.0f;
#pragma unroll
        for (int r = 0; r < 4; r++) {
            p0[r] = __expf(v0[r] - mnew);
            p1[r] = __expf(v1[r] - mnew);
            tsum += p0[r] + p1[r];
        }
        tsum += __shfl_xor(tsum, 16);
        tsum += __shfl_xor(tsum, 32);
        l = l * alpha + tsum;
        m = mnew;
#pragma unroll
        for (int t = 0; t < 8; t++) {
            ctx[t][0] *= alpha; ctx[t][1] *= alpha;
            ctx[t][2] *= alpha; ctx[t][3] *= alpha;
        }
#pragma unroll
        for (int r = 0; r < 4; r++) {
            pls[wave][l15][quad * 4 + r]      = f2b(p0[r]);
            pls[wave][l15][16 + quad * 4 + r] = f2b(p1[r]);
        }
        bf16x8 pf = *(const bf16x8*)&pls[wave][l15][quad * 8];
        const short* vp = (const short*)(Vb + ((size_t)hl * Ss + kb) * HD);
#pragma unroll
        for (int t = 0; t < 8; t++) {
            bf16x8 vf;
#pragma unroll
            for (int j = 0; j < 8; j++) {
                short sv = vp[(size_t)(quad * 8 + j) * HD + t * 16 + l15];
                vf[j] = __builtin_bit_cast(bf16, sv);
            }
            ctx[t] = __builtin_amdgcn_mfma_f32_16x16x32_bf16(vf, pf, ctx[t], 0, 0, 0);
        }
    }
    float inv = 1.0f / l;
    bf16* op = Obase + (size_t)qg * HID + hl * HD;
#pragma unroll
    for (int t = 0; t < 8; t++) {
        bf16x4 ov;
#pragma unroll
        for (int r = 0; r < 4; r++) ov[r] = f2b(ctx[t][r] * inv);
        *(bf16x4*)(op + t * 16 + quad * 4) = ov;
    }
}

__global__ __launch_bounds__(256) void gemm_out_f32(
    const bf16* __restrict__ A, const float* __restrict__ B,
    float* __restrict__ C, int N, int K)
{
    int tid = threadIdx.x, lane = tid & 63, wave = tid >> 6;
    int l15 = lane & 15, quad = lane >> 4;
    int m0 = blockIdx.x * 128 + (wave >> 1) * 64;
    int n0 = blockIdx.y * 128 + (wave & 1) * 64;

    floatx4 acc[4][4] = {};
    const bf16*  ap = A + (size_t)(m0 + l15) * K + quad * 8;
    const float* bp = B + (size_t)(n0 + l15) * K + quad * 8;
    for (int k0 = 0; k0 < K; k0 += 32) {
        bf16x8 a[4], b[4];
#pragma unroll
        for (int i = 0; i < 4; i++) {
            a[i] = *(const bf16x8*)(ap + (size_t)i * 16 * K + k0);
            b[i] = load8_f32(bp + (size_t)i * 16 * K + k0);
        }
#pragma unroll
        for (int i = 0; i < 4; i++)
#pragma unroll
            for (int j = 0; j < 4; j++)
                acc[i][j] = __builtin_amdgcn_mfma_f32_16x16x32_bf16(a[i], b[j], acc[i][j], 0, 0, 0);
    }
#pragma unroll
    for (int i = 0; i < 4; i++)
#pragma unroll
        for (int j = 0; j < 4; j++) {
            int row = m0 + i * 16 + quad * 4;
            int col = n0 + j * 16 + l15;
#pragma unroll
            for (int r = 0; r < 4; r++)
                C[(size_t)(row + r) * N + col] = acc[i][j][r];
        }
}

extern "C" void kernel_launch(void* const* d_in, const int* in_sizes, int n_in,
                              void* d_out, int out_size, void* d_ws, size_t ws_size,
                              hipStream_t stream)
{
    const float *x = nullptr, *w_qkv = nullptr, *w_o = nullptr;
    const float *t0 = nullptr, *t1 = nullptr;
    for (int i = 0; i < n_in; i++) {
        const float* p = (const float*)d_in[i];
        if      (in_sizes[i] == 12582912) w_qkv = p;
        else if (in_sizes[i] ==  8388608) x     = p;
        else if (in_sizes[i] ==  4194304) w_o   = p;
        else if (in_sizes[i] ==   262144) { if (t0) t1 = p; else t0 = p; }
    }
    float* out = (float*)d_out;
    char* ws = (char*)d_ws;

    if (ws_size >= (size_t)67108864) {
        // ---------------- PATH A ----------------
        bf16* xb  = (bf16*)ws;                       // 16.78 MB
        bf16* wqb = (bf16*)(ws + 16777216);          // 25.17 MB
        bf16* wob = (bf16*)(ws + 41943040);          // 8.39 MB
        bf16* ctx = (bf16*)ws;                       // reuse xb after qkv
        bf16 *qb, *kbuf, *vT;
        if (ws_size >= (size_t)100663296) {          // A1: all in ws
            qb   = (bf16*)(ws + 50331648);
            kbuf = (bf16*)(ws + 67108864);
            vT   = (bf16*)(ws + 83886080);
        } else {                                     // A2: q,k in d_out scratch
            qb   = (bf16*)d_out;
            kbuf = (bf16*)((char*)d_out + 16777216);
            vT   = (bf16*)(ws + 50331648);
        }

        cvt_all<<<2048, 256, 0, stream>>>(x, w_qkv, w_o, xb, wqb, wob);

        qkv_gemm_rope<<<dim3(32, 48), 256, 0, stream>>>(xb, wqb, t0, t1, qb, kbuf, vT);
        attn_full<<<dim3(512), 256, 0, stream>>>(qb, kbuf, vT, ctx);
        out_gemm<<<dim3(32, 16), 256, 0, stream>>>(ctx, wob, out);
    } else {
        // ---------------- PATH B (round-8 fallback) ----------------
        const size_t pe = (size_t)HG * Ss * HD;
        bf16* qc = (bf16*)d_ws;
        bf16* kc = qc + pe;
        bf16* vc = kc + pe;
        float* fin = (float*)d_ws;
        bf16* ctx = (bf16*)((char*)d_out + (size_t)16777216);

        for (int bi = 0; bi < Bb; bi++) {
            const float* xbp = x + (size_t)bi * Ss * HID;
            for (int hg = 0; hg < 2; hg++) {
                qkv_rope_pass<<<dim3(Ss / 128, 24), 256, 0, stream>>>(
                    xbp, w_qkv, t0, t1, qc, kc, vc, hg);
                bf16* Obase = ctx + (size_t)bi * Ss * HID + (size_t)hg * HG * HD;
                attn_pass<<<dim3(HG, Ss / 64), 256, 0, stream>>>(qc, kc, vc, Obase);
            }
        }
        gemm_out_f32<<<dim3(16, 16), 256, 0, stream>>>(ctx, w_o, fin, HID, HID);
        hipMemcpyAsync(out, fin, (size_t)2048 * HID * sizeof(float),
                       hipMemcpyDeviceToDevice, stream);
        gemm_out_f32<<<dim3(16, 16), 256, 0, stream>>>(ctx + (size_t)2048 * HID, w_o,
                                                       fin, HID, HID);
        hipMemcpyAsync(out + (size_t)2048 * HID, fin, (size_t)2048 * HID * sizeof(float),
                       hipMemcpyDeviceToDevice, stream);
    }
}

// Round 9
// 372.514 us; speedup vs baseline: 1.0814x; 1.0814x over previous
//
#include <hip/hip_runtime.h>
#include <hip/hip_bf16.h>

typedef __bf16 bf16;
typedef __bf16 bf16x4 __attribute__((ext_vector_type(4)));
typedef __bf16 bf16x8 __attribute__((ext_vector_type(8)));
typedef float floatx4 __attribute__((ext_vector_type(4)));

#define Bb   2
#define Ss   2048
#define HID  2048
#define NH   16
#define HD   128
#define HG   8

typedef __attribute__((address_space(3))) unsigned int lds_u32;
typedef const __attribute__((address_space(1))) unsigned int gbl_u32;

__device__ __forceinline__ float b2f(bf16 h) {
    unsigned short u = __builtin_bit_cast(unsigned short, h);
    unsigned int x = ((unsigned int)u) << 16;
    return __builtin_bit_cast(float, x);
}
__device__ __forceinline__ bf16 f2b(float f) {
    __hip_bfloat16 t = __float2bfloat16(f);
    return __builtin_bit_cast(bf16, t);
}
__device__ __forceinline__ bf16x8 load8_f32(const float* p) {
    float4 u = *(const float4*)p;
    float4 v = *(const float4*)(p + 4);
    bf16x8 r;
    r[0] = f2b(u.x); r[1] = f2b(u.y); r[2] = f2b(u.z); r[3] = f2b(u.w);
    r[4] = f2b(v.x); r[5] = f2b(v.y); r[6] = f2b(v.z); r[7] = f2b(v.w);
    return r;
}
// async global->LDS, 16B per lane; lds base must be wave-uniform
__device__ __forceinline__ void stage16(const bf16* g, bf16* l) {
    __builtin_amdgcn_global_load_lds((gbl_u32*)g, (lds_u32*)l, 16, 0, 0);
}

// ===========================================================================
// PATH A kernels (ws >= 64 MiB)
// ===========================================================================

// merged f32->bf16 conversion for x (2.10M f4), w_qkv (3.15M f4), w_o (1.05M f4)
__global__ __launch_bounds__(256) void cvt_all(
    const float* __restrict__ x, const float* __restrict__ wq,
    const float* __restrict__ wo,
    bf16* __restrict__ xb, bf16* __restrict__ wqb, bf16* __restrict__ wob)
{
    int idx = blockIdx.x * 256 + threadIdx.x;
    int stride = gridDim.x * 256;
    for (int i = idx; i < 6291456; i += stride) {
        const float* in; bf16* out; int k;
        if (i < 2097152)      { in = x;  out = xb;  k = i; }
        else if (i < 5242880) { in = wq; out = wqb; k = i - 2097152; }
        else                  { in = wo; out = wob; k = i - 5242880; }
        float4 v = ((const float4*)in)[k];
        bf16x4 o; o[0] = f2b(v.x); o[1] = f2b(v.y); o[2] = f2b(v.z); o[3] = f2b(v.w);
        ((bf16x4*)out)[k] = o;
    }
}

// ---------------------------------------------------------------------------
// Single-dispatch QKV GEMM + RoPE + head-split, v3: BK=64.
//  2-phase critical path is stage+vmcnt+barrier (m233: ~72%); BK=32->64
//  halves barrier count per unit K at UNCHANGED occupancy (LDS 32KB vs the
//  33.8KB epilogue overlay already resident -> still 4 blocks/CU).
//  [128][64] rows are 128B -> XOR-swizzle col^(8*(row&7)) on LDS reads,
//  with the global SOURCE col pre-swizzled by the same involution
//  (global_load_lds writes linearly; rule #21 both-sides-or-neither).
// ---------------------------------------------------------------------------
__global__ __launch_bounds__(256) void qkv_gemm_rope(
    const bf16* __restrict__ xb, const bf16* __restrict__ wqb,
    const float* __restrict__ c0, const float* __restrict__ c1,
    bf16* __restrict__ q, bf16* __restrict__ k, bf16* __restrict__ vT)
{
    __shared__ __attribute__((aligned(16))) char smem[128 * 132 * 2];
    bf16* As = (bf16*)smem;                 // [128][64] = 16 KB (K-loop only)
    bf16* Bs = (bf16*)(smem + 16384);       // [128][64] = 16 KB (K-loop only)
    typedef bf16 (*tile_t)[132];
    tile_t tile = (tile_t)smem;             // [128][132] (epilogue overlay)

    bool c0cos = (c0[0] > 0.5f);
    const float* cosT = c0cos ? c0 : c1;
    const float* sinT = c0cos ? c1 : c0;

    int tid = threadIdx.x, lane = tid & 63, w = tid >> 6;
    int l15 = lane & 15, quad = lane >> 4;
    int m0 = blockIdx.x * 128, n0 = blockIdx.y * 128;
    int mw = (w >> 1) * 64, nw = (w & 1) * 64;

    // staging: wave w rows [w*32, w*32+32), 8 rows per 1KB issue.
    // source col pre-swizzled: lane covers LDS (row, c0=(lane&7)*8) and must
    // load global col c0 ^ 8*(row&7), row&7 = lane>>3.
    int srow = w * 32 + (lane >> 3);
    int scol = ((lane & 7) ^ (lane >> 3)) * 8;
    const bf16* ga = xb  + (size_t)(m0 + srow) * HID + scol;
    const bf16* gb = wqb + (size_t)(n0 + srow) * HID + scol;
    bf16* la = As + w * 2048;
    bf16* lb = Bs + w * 2048;

    int sw = (l15 & 7) * 8;                 // read-side swizzle (row&7 = l15&7)

    floatx4 acc[4][4] = {};
    for (int k0 = 0; k0 < HID; k0 += 64) {
#pragma unroll
        for (int i = 0; i < 4; i++) {
            stage16(ga + (size_t)(i * 8) * HID + k0, la + i * 512);
            stage16(gb + (size_t)(i * 8) * HID + k0, lb + i * 512);
        }
        __syncthreads();
#pragma unroll
        for (int ks = 0; ks < 2; ks++) {
            int cb = (ks * 32 + quad * 8) ^ sw;
            bf16x8 a[4], b[4];
#pragma unroll
            for (int i = 0; i < 4; i++) {
                a[i] = *(const bf16x8*)&As[(mw + i * 16 + l15) * 64 + cb];
                b[i] = *(const bf16x8*)&Bs[(nw + i * 16 + l15) * 64 + cb];
            }
#pragma unroll
            for (int i = 0; i < 4; i++)
#pragma unroll
                for (int j = 0; j < 4; j++)
                    acc[i][j] = __builtin_amdgcn_mfma_f32_16x16x32_bf16(a[i], b[j], acc[i][j], 0, 0, 0);
        }
        __syncthreads();
    }
    // after the final __syncthreads: no As/Bs readers remain, all DMAs
    // drained -> safe to overlay tile on the same LDS.

#pragma unroll
    for (int i = 0; i < 4; i++)
#pragma unroll
        for (int j = 0; j < 4; j++) {
            int row_l = mw + i * 16 + quad * 4;
            int col_l = nw + j * 16 + l15;
#pragma unroll
            for (int r = 0; r < 4; r++)
                tile[row_l + r][col_l] = f2b(acc[i][j][r]);
        }
    __syncthreads();

    int sec = blockIdx.y >> 4;
    int h   = blockIdx.y & 15;
    int bi  = m0 >> 11;
    int bh  = bi * NH + h;
    int sbase = m0 & (Ss - 1);

    if (sec == 2) {
        int d  = tid >> 1;
        int sh = (tid & 1) * 64;
        bf16* vrow = vT + ((size_t)bh * HD + d) * Ss + sbase + sh;
#pragma unroll 4
        for (int i = 0; i < 64; i += 4) {
            bf16x4 pk;
#pragma unroll
            for (int r = 0; r < 4; r++) pk[r] = tile[sh + i + r][d];
            *(bf16x4*)(vrow + i) = pk;
        }
    } else {
        bf16* dst = (sec == 0) ? q : k;
        int d  = tid & 63;
        int r0 = tid >> 6;
#pragma unroll 4
        for (int it = 0; it < 32; it++) {
            int row_l = it * 4 + r0;
            int s = sbase + row_l;
            float x1 = b2f(tile[row_l][d]);
            float x2 = b2f(tile[row_l][d + 64]);
            float cc1 = cosT[s * HD + d];
            float ss1 = sinT[s * HD + d];
            float cc2 = cosT[s * HD + d + 64];
            float ss2 = sinT[s * HD + d + 64];
            size_t o = ((size_t)bh * Ss + s) * HD + d;
            dst[o]      = f2b(x1 * cc1 - x2 * ss1);
            dst[o + 64] = f2b(x2 * cc2 + x1 * ss2);
        }
    }
}

// ---------------------------------------------------------------------------
// Full-grid causal flash attention (r4/r6 version — local optimum: LDS-shared
// K/V, 2 buffers, 16q/wave, 4 blocks/CU. r5 pipeline / r8 32q both regressed
// by trading block-level TLP away.)
// ---------------------------------------------------------------------------
#define ATTN_C1 (0.08838834764831845f * 1.44269504f)   /* scale * log2(e) */

#define STAGE_KV(BUF, KB)                                                        \
{                                                                                \
    const char* kg = kgbase + (size_t)(KB) * 256;                                \
    const char* vg = vgbase + (size_t)(KB) * 2;                                  \
    _Pragma("unroll")                                                            \
    for (int i = 0; i < 2; i++) {                                                \
        int P  = P0 + i * 1024;                                                  \
        int r  = P >> 8;                                                         \
        int cK = (P & 255) ^ ((r & 7) << 4);                                     \
        stage16((const bf16*)(kg + r * 256 + cK),                                \
                (bf16*)((char*)Kls[BUF] + wave * 2048 + i * 1024));              \
        int d  = P >> 6;                                                         \
        int cV = (P & 63) ^ (((d >> 1) & 3) << 4);                               \
        stage16((const bf16*)(vg + (size_t)d * 4096 + cV),                       \
                (bf16*)((char*)Vls[BUF] + wave * 2048 + i * 1024));              \
    }                                                                            \
}

__global__ __launch_bounds__(256, 4) void attn_full(
    const bf16* __restrict__ Q, const bf16* __restrict__ Kb, const bf16* __restrict__ VT,
    bf16* __restrict__ O)
{
    __shared__ __attribute__((aligned(16))) bf16 Kls[2][32 * 128];
    __shared__ __attribute__((aligned(16))) bf16 Vls[2][128 * 32];
    __shared__ bf16 pls[4][16][40];

    // XCD-locality swizzle: 4 heads per XCD slot, big q-tiles first.
    int id   = blockIdx.x;
    int xcd  = id & 7;
    int j    = id >> 3;
    int bh   = (xcd << 2) | (j & 3);
    int qt   = 31 - (j >> 2);

    int tid  = threadIdx.x;
    int wave = tid >> 6;
    int lane = tid & 63;
    int l15  = lane & 15;
    int quad = lane >> 4;

    int q0 = qt * 64 + wave * 16;
    int qg = q0 + l15;

    const char* kgbase = (const char*)(Kb + (size_t)bh * Ss * HD);
    const char* vgbase = (const char*)(VT + (size_t)bh * HD * Ss);
    int P0 = wave * 2048 + lane * 16;

    // stage tile 0 into buf 0 ASAP
    STAGE_KV(0, 0);

    const bf16* qptr = Q + ((size_t)bh * Ss + qg) * HD + quad * 8;
    bf16x8 qf[4];
#pragma unroll
    for (int s = 0; s < 4; s++) qf[s] = *(const bf16x8*)(qptr + s * 32);

    float m    = -1e30f;
    float bm   = 1.44269504e30f;   // = -m * log2(e); first step always rescales
    float lsum = 0.0f;             // per-lane partial; reduced in epilogue
    floatx4 ctx[8] = {};

    int nsteps = 2 * qt + 2;       // block-uniform trip count (wave 3's need)
    int buf = 0;
    __syncthreads();               // tile 0 ready (syncthreads drains vmcnt)

    for (int st = 0; st < nsteps; st++) {
        int kb = st * 32;
        if (st + 1 < nsteps) {
            int bufn = buf ^ 1;
            STAGE_KV(bufn, kb + 32);
        }
        if (kb <= q0 + 15) {
            bool masked = (kb + 31 > q0);   // wave-uniform
            const char* kls = (const char*)Kls[buf];
            const char* vls = (const char*)Vls[buf];

            floatx4 s0 = {0.f,0.f,0.f,0.f}, s1 = {0.f,0.f,0.f,0.f};
            __builtin_amdgcn_s_setprio(1);
#pragma unroll
            for (int s = 0; s < 4; s++) {
                int c = (quad * 16 + s * 64) ^ ((l15 & 7) << 4);
                bf16x8 k0 = *(const bf16x8*)(kls + l15 * 256 + c);
                bf16x8 k1 = *(const bf16x8*)(kls + (l15 + 16) * 256 + c);
                s0 = __builtin_amdgcn_mfma_f32_16x16x32_bf16(k0, qf[s], s0, 0, 0, 0);
                s1 = __builtin_amdgcn_mfma_f32_16x16x32_bf16(k1, qf[s], s1, 0, 0, 0);
            }
            __builtin_amdgcn_s_setprio(0);

            float v0[4], v1[4];
#pragma unroll
            for (int r = 0; r < 4; r++) {
                int key0 = kb + quad * 4 + r;
                v0[r] = (masked && key0 > qg)      ? -1e9f : s0[r];
                v1[r] = (masked && key0 + 16 > qg) ? -1e9f : s1[r];
            }
            // per-lane local max -> wave-uniform defer check (no shuffles)
            float lmax = fmaxf(fmaxf(fmaxf(v0[0], v0[1]), fmaxf(v0[2], v0[3])),
                               fmaxf(fmaxf(v1[0], v1[1]), fmaxf(v1[2], v1[3])));
            if (!__all(lmax * 0.08838834764831845f <= m + 8.0f)) {
                float tm = lmax;
                tm = fmaxf(tm, __shfl_xor(tm, 16));
                tm = fmaxf(tm, __shfl_xor(tm, 32));
                float tms  = tm * 0.08838834764831845f;
                float mnew = fmaxf(m, tms);
                float bmn  = -mnew * 1.44269504f;
                float alpha = __builtin_exp2f(bmn - bm);
                m = mnew; bm = bmn;
                lsum *= alpha;
#pragma unroll
                for (int t = 0; t < 8; t++) {
                    ctx[t][0] *= alpha; ctx[t][1] *= alpha;
                    ctx[t][2] *= alpha; ctx[t][3] *= alpha;
                }
            }
            bf16x4 pk0, pk1; float ts = 0.f;
#pragma unroll
            for (int r = 0; r < 4; r++) {
                float pe0 = __builtin_exp2f(__builtin_fmaf(v0[r], ATTN_C1, bm));
                float pe1 = __builtin_exp2f(__builtin_fmaf(v1[r], ATTN_C1, bm));
                ts += pe0 + pe1;
                pk0[r] = f2b(pe0); pk1[r] = f2b(pe1);
            }
            lsum += ts;
            *(bf16x4*)&pls[wave][l15][quad * 4]      = pk0;
            *(bf16x4*)&pls[wave][l15][16 + quad * 4] = pk1;
            bf16x8 pf = *(const bf16x8*)&pls[wave][l15][quad * 8];

            __builtin_amdgcn_s_setprio(1);
#pragma unroll
            for (int t = 0; t < 8; t++) {
                int row = t * 16 + l15;
                bf16x8 vf = *(const bf16x8*)(vls + row * 64 +
                                             ((quad * 16) ^ (((row >> 1) & 3) << 4)));
                ctx[t] = __builtin_amdgcn_mfma_f32_16x16x32_bf16(vf, pf, ctx[t], 0, 0, 0);
            }
            __builtin_amdgcn_s_setprio(0);
        }
        __syncthreads();           // staged tile complete + all reads of buf done
        buf ^= 1;
    }

    // epilogue: cross-lane l reduction (once)
    lsum += __shfl_xor(lsum, 16);
    lsum += __shfl_xor(lsum, 32);
    float inv = 1.0f / lsum;

    int bi = bh >> 4, h = bh & (NH - 1);
    bf16* op = O + ((size_t)(bi * Ss + qg)) * HID + h * HD;
#pragma unroll
    for (int t = 0; t < 8; t++) {
        bf16x4 ov;
#pragma unroll
        for (int r = 0; r < 4; r++) ov[r] = f2b(ctx[t][r] * inv);
        *(bf16x4*)(op + t * 16 + quad * 4) = ov;
    }
}

// ---------------------------------------------------------------------------
// Out-projection v3: 128x128 tile (r6) + BK=64 swizzled staging (same
// transformation as qkv_gemm_rope v3). Grid (32,16) = 2 blocks/CU, LDS 32KB.
// ---------------------------------------------------------------------------
__global__ __launch_bounds__(256) void out_gemm(
    const bf16* __restrict__ A, const bf16* __restrict__ B, float* __restrict__ C)
{
    __shared__ __attribute__((aligned(16))) bf16 As[128 * 64];
    __shared__ __attribute__((aligned(16))) bf16 Bs[128 * 64];

    int tid = threadIdx.x, lane = tid & 63, w = tid >> 6;
    int l15 = lane & 15, quad = lane >> 4;
    int m0 = blockIdx.x * 128, n0 = blockIdx.y * 128;
    int mw = (w >> 1) * 64, nw = (w & 1) * 64;

    int srow = w * 32 + (lane >> 3);
    int scol = ((lane & 7) ^ (lane >> 3)) * 8;
    const bf16* ga = A + (size_t)(m0 + srow) * HID + scol;
    const bf16* gb = B + (size_t)(n0 + srow) * HID + scol;
    bf16* la = As + w * 2048;
    bf16* lb = Bs + w * 2048;

    int sw = (l15 & 7) * 8;

    floatx4 acc[4][4] = {};
    for (int k0 = 0; k0 < HID; k0 += 64) {
#pragma unroll
        for (int i = 0; i < 4; i++) {
            stage16(ga + (size_t)(i * 8) * HID + k0, la + i * 512);
            stage16(gb + (size_t)(i * 8) * HID + k0, lb + i * 512);
        }
        __syncthreads();
#pragma unroll
        for (int ks = 0; ks < 2; ks++) {
            int cb = (ks * 32 + quad * 8) ^ sw;
            bf16x8 a[4], b[4];
#pragma unroll
            for (int i = 0; i < 4; i++) {
                a[i] = *(const bf16x8*)&As[(mw + i * 16 + l15) * 64 + cb];
                b[i] = *(const bf16x8*)&Bs[(nw + i * 16 + l15) * 64 + cb];
            }
#pragma unroll
            for (int i = 0; i < 4; i++)
#pragma unroll
                for (int j = 0; j < 4; j++)
                    acc[i][j] = __builtin_amdgcn_mfma_f32_16x16x32_bf16(a[i], b[j], acc[i][j], 0, 0, 0);
        }
        __syncthreads();
    }

#pragma unroll
    for (int i = 0; i < 4; i++)
#pragma unroll
        for (int j = 0; j < 4; j++) {
            int row = m0 + mw + i * 16 + quad * 4;
            int col = n0 + nw + j * 16 + l15;
#pragma unroll
            for (int r = 0; r < 4; r++)
                C[(size_t)(row + r) * HID + col] = acc[i][j][r];
        }
}

// ===========================================================================
// PATH B kernels (round-8 fallback, ws < 64 MiB) — proven passing
// ===========================================================================

__global__ __launch_bounds__(256) void qkv_rope_pass(
    const float* __restrict__ xb, const float* __restrict__ W,
    const float* __restrict__ c0, const float* __restrict__ c1,
    bf16* __restrict__ qc, bf16* __restrict__ kc, bf16* __restrict__ vc, int hg)
{
    __shared__ bf16 tile[128][132];
    bool c0cos = (c0[0] > 0.5f);
    const float* cosT = c0cos ? c0 : c1;
    const float* sinT = c0cos ? c1 : c0;

    int tid = threadIdx.x, lane = tid & 63, wave = tid >> 6;
    int l15 = lane & 15, quad = lane >> 4;
    int sec = blockIdx.y >> 3, hl = blockIdx.y & 7;
    int nbase = sec * (NH * HD) + (hg * HG + hl) * HD;
    int m0 = blockIdx.x * 128 + (wave >> 1) * 64;
    int n0l = (wave & 1) * 64;

    floatx4 acc[4][4] = {};
    const float* ap = xb + (size_t)(m0 + l15) * HID + quad * 8;
    const float* bp = W  + (size_t)(nbase + n0l + l15) * HID + quad * 8;
    for (int k0 = 0; k0 < HID; k0 += 32) {
        bf16x8 a[4], b[4];
#pragma unroll
        for (int i = 0; i < 4; i++) {
            a[i] = load8_f32(ap + (size_t)i * 16 * HID + k0);
            b[i] = load8_f32(bp + (size_t)i * 16 * HID + k0);
        }
#pragma unroll
        for (int i = 0; i < 4; i++)
#pragma unroll
            for (int j = 0; j < 4; j++)
                acc[i][j] = __builtin_amdgcn_mfma_f32_16x16x32_bf16(a[i], b[j], acc[i][j], 0, 0, 0);
    }
    int lr = (wave >> 1) * 64;
#pragma unroll
    for (int i = 0; i < 4; i++)
#pragma unroll
        for (int j = 0; j < 4; j++) {
            int row_l = lr + i * 16 + quad * 4;
            int col_l = n0l + j * 16 + l15;
#pragma unroll
            for (int r = 0; r < 4; r++)
                tile[row_l + r][col_l] = f2b(acc[i][j][r]);
        }
    __syncthreads();

    bf16* dst = (sec == 0) ? qc : (sec == 1) ? kc : vc;
    int d = tid & 63, r0 = tid >> 6;
#pragma unroll 4
    for (int it = 0; it < 32; it++) {
        int row_l = it * 4 + r0;
        int s = blockIdx.x * 128 + row_l;
        float x1 = b2f(tile[row_l][d]);
        float x2 = b2f(tile[row_l][d + 64]);
        size_t o = ((size_t)hl * Ss + s) * HD + d;
        if (sec == 2) { dst[o] = f2b(x1); dst[o + 64] = f2b(x2); }
        else {
            float cc1 = cosT[s * HD + d], ss1 = sinT[s * HD + d];
            float cc2 = cosT[s * HD + d + 64], ss2 = sinT[s * HD + d + 64];
            dst[o]      = f2b(x1 * cc1 - x2 * ss1);
            dst[o + 64] = f2b(x2 * cc2 + x1 * ss2);
        }
    }
}

__global__ __launch_bounds__(256) void attn_pass(
    const bf16* __restrict__ Q, const bf16* __restrict__ Kb, const bf16* __restrict__ Vb,
    bf16* __restrict__ Obase)
{
    __shared__ bf16 pls[4][16][40];
    int hl = blockIdx.x;
    int qt = (gridDim.y - 1) - blockIdx.y;
    int tid = threadIdx.x, wave = tid >> 6, lane = tid & 63;
    int l15 = lane & 15, quad = lane >> 4;
    int q0 = qt * 64 + wave * 16;
    int qg = q0 + l15;

    const bf16* qptr = Q + ((size_t)hl * Ss + qg) * HD + quad * 8;
    bf16x8 qf[4];
#pragma unroll
    for (int s = 0; s < 4; s++) qf[s] = *(const bf16x8*)(qptr + s * 32);

    float m = -1e30f, l = 0.0f;
    floatx4 ctx[8] = {};
    const float scale = 0.08838834764831845f;

    for (int kb = 0; kb <= q0 + 15; kb += 32) {
        floatx4 s0 = {0.f,0.f,0.f,0.f}, s1 = {0.f,0.f,0.f,0.f};
        const bf16* kp0 = Kb + ((size_t)hl * Ss + kb + l15) * HD + quad * 8;
        const bf16* kp1 = kp0 + (size_t)16 * HD;
#pragma unroll
        for (int s = 0; s < 4; s++) {
            bf16x8 k0 = *(const bf16x8*)(kp0 + s * 32);
            bf16x8 k1 = *(const bf16x8*)(kp1 + s * 32);
            s0 = __builtin_amdgcn_mfma_f32_16x16x32_bf16(k0, qf[s], s0, 0, 0, 0);
            s1 = __builtin_amdgcn_mfma_f32_16x16x32_bf16(k1, qf[s], s1, 0, 0, 0);
        }
        float v0[4], v1[4];
#pragma unroll
        for (int r = 0; r < 4; r++) {
            int key0 = kb + quad * 4 + r;
            v0[r] = (key0 > qg)      ? -1e9f : s0[r] * scale;
            v1[r] = (key0 + 16 > qg) ? -1e9f : s1[r] * scale;
        }
        float tmax = fmaxf(fmaxf(fmaxf(v0[0], v0[1]), fmaxf(v0[2], v0[3])),
                           fmaxf(fmaxf(v1[0], v1[1]), fmaxf(v1[2], v1[3])));
        tmax = fmaxf(tmax, __shfl_xor(tmax, 16));
        tmax = fmaxf(tmax, __shfl_xor(tmax, 32));
        float mnew = fmaxf(m, tmax);
        float alpha = __expf(m - mnew);
        float p0[4], p1[4], tsum = 0.0f;
#pragma unroll
        for (int r = 0; r < 4; r++) {
            p0[r] = __expf(v0[r] - mnew);
            p1[r] = __expf(v1[r] - mnew);
            tsum += p0[r] + p1[r];
        }
        tsum += __shfl_xor(tsum, 16);
        tsum += __shfl_xor(tsum, 32);
        l = l * alpha + tsum;
        m = mnew;
#pragma unroll
        for (int t = 0; t < 8; t++) {
            ctx[t][0] *= alpha; ctx[t][1] *= alpha;
            ctx[t][2] *= alpha; ctx[t][3] *= alpha;
        }
#pragma unroll
        for (int r = 0; r < 4; r++) {
            pls[wave][l15][quad * 4 + r]      = f2b(p0[r]);
            pls[wave][l15][16 + quad * 4 + r] = f2b(p1[r]);
        }
        bf16x8 pf = *(const bf16x8*)&pls[wave][l15][quad * 8];
        const short* vp = (const short*)(Vb + ((size_t)hl * Ss + kb) * HD);
#pragma unroll
        for (int t = 0; t < 8; t++) {
            bf16x8 vf;
#pragma unroll
            for (int j = 0; j < 8; j++) {
                short sv = vp[(size_t)(quad * 8 + j) * HD + t * 16 + l15];
                vf[j] = __builtin_bit_cast(bf16, sv);
            }
            ctx[t] = __builtin_amdgcn_mfma_f32_16x16x32_bf16(vf, pf, ctx[t], 0, 0, 0);
        }
    }
    float inv = 1.0f / l;
    bf16* op = Obase + (size_t)qg * HID + hl * HD;
#pragma unroll
    for (int t = 0; t < 8; t++) {
        bf16x4 ov;
#pragma unroll
        for (int r = 0; r < 4; r++) ov[r] = f2b(ctx[t][r] * inv);
        *(bf16x4*)(op + t * 16 + quad * 4) = ov;
    }
}

__global__ __launch_bounds__(256) void gemm_out_f32(
    const bf16* __restrict__ A, const float* __restrict__ B,
    float* __restrict__ C, int N, int K)
{
    int tid = threadIdx.x, lane = tid & 63, wave = tid >> 6;
    int l15 = lane & 15, quad = lane >> 4;
    int m0 = blockIdx.x * 128 + (wave >> 1) * 64;
    int n0 = blockIdx.y * 128 + (wave & 1) * 64;

    floatx4 acc[4][4] = {};
    const bf16*  ap = A + (size_t)(m0 + l15) * K + quad * 8;
    const float* bp = B + (size_t)(n0 + l15) * K + quad * 8;
    for (int k0 = 0; k0 < K; k0 += 32) {
        bf16x8 a[4], b[4];
#pragma unroll
        for (int i = 0; i < 4; i++) {
            a[i] = *(const bf16x8*)(ap + (size_t)i * 16 * K + k0);
            b[i] = load8_f32(bp + (size_t)i * 16 * K + k0);
        }
#pragma unroll
        for (int i = 0; i < 4; i++)
#pragma unroll
            for (int j = 0; j < 4; j++)
                acc[i][j] = __builtin_amdgcn_mfma_f32_16x16x32_bf16(a[i], b[j], acc[i][j], 0, 0, 0);
    }
#pragma unroll
    for (int i = 0; i < 4; i++)
#pragma unroll
        for (int j = 0; j < 4; j++) {
            int row = m0 + i * 16 + quad * 4;
            int col = n0 + j * 16 + l15;
#pragma unroll
            for (int r = 0; r < 4; r++)
                C[(size_t)(row + r) * N + col] = acc[i][j][r];
        }
}

extern "C" void kernel_launch(void* const* d_in, const int* in_sizes, int n_in,
                              void* d_out, int out_size, void* d_ws, size_t ws_size,
                              hipStream_t stream)
{
    const float *x = nullptr, *w_qkv = nullptr, *w_o = nullptr;
    const float *t0 = nullptr, *t1 = nullptr;
    for (int i = 0; i < n_in; i++) {
        const float* p = (const float*)d_in[i];
        if      (in_sizes[i] == 12582912) w_qkv = p;
        else if (in_sizes[i] ==  8388608) x     = p;
        else if (in_sizes[i] ==  4194304) w_o   = p;
        else if (in_sizes[i] ==   262144) { if (t0) t1 = p; else t0 = p; }
    }
    float* out = (float*)d_out;
    char* ws = (char*)d_ws;

    if (ws_size >= (size_t)67108864) {
        // ---------------- PATH A ----------------
        bf16* xb  = (bf16*)ws;                       // 16.78 MB
        bf16* wqb = (bf16*)(ws + 16777216);          // 25.17 MB
        bf16* wob = (bf16*)(ws + 41943040);          // 8.39 MB
        bf16* ctx = (bf16*)ws;                       // reuse xb after qkv
        bf16 *qb, *kbuf, *vT;
        if (ws_size >= (size_t)100663296) {          // A1: all in ws
            qb   = (bf16*)(ws + 50331648);
            kbuf = (bf16*)(ws + 67108864);
            vT   = (bf16*)(ws + 83886080);
        } else {                                     // A2: q,k in d_out scratch
            qb   = (bf16*)d_out;
            kbuf = (bf16*)((char*)d_out + 16777216);
            vT   = (bf16*)(ws + 50331648);
        }

        cvt_all<<<2048, 256, 0, stream>>>(x, w_qkv, w_o, xb, wqb, wob);

        qkv_gemm_rope<<<dim3(32, 48), 256, 0, stream>>>(xb, wqb, t0, t1, qb, kbuf, vT);
        attn_full<<<dim3(1024), 256, 0, stream>>>(qb, kbuf, vT, ctx);
        out_gemm<<<dim3(32, 16), 256, 0, stream>>>(ctx, wob, out);
    } else {
        // ---------------- PATH B (round-8 fallback) ----------------
        const size_t pe = (size_t)HG * Ss * HD;
        bf16* qc = (bf16*)d_ws;
        bf16* kc = qc + pe;
        bf16* vc = kc + pe;
        float* fin = (float*)d_ws;
        bf16* ctx = (bf16*)((char*)d_out + (size_t)16777216);

        for (int bi = 0; bi < Bb; bi++) {
            const float* xbp = x + (size_t)bi * Ss * HID;
            for (int hg = 0; hg < 2; hg++) {
                qkv_rope_pass<<<dim3(Ss / 128, 24), 256, 0, stream>>>(
                    xbp, w_qkv, t0, t1, qc, kc, vc, hg);
                bf16* Obase = ctx + (size_t)bi * Ss * HID + (size_t)hg * HG * HD;
                attn_pass<<<dim3(HG, Ss / 64), 256, 0, stream>>>(qc, kc, vc, Obase);
            }
        }
        gemm_out_f32<<<dim3(16, 16), 256, 0, stream>>>(ctx, w_o, fin, HID, HID);
        hipMemcpyAsync(out, fin, (size_t)2048 * HID * sizeof(float),
                       hipMemcpyDeviceToDevice, stream);
        gemm_out_f32<<<dim3(16, 16), 256, 0, stream>>>(ctx + (size_t)2048 * HID, w_o,
                                                       fin, HID, HID);
        hipMemcpyAsync(out + (size_t)2048 * HID, fin, (size_t)2048 * HID * sizeof(float),
                       hipMemcpyDeviceToDevice, stream);
    }
}

// Round 10
// 369.146 us; speedup vs baseline: 1.0912x; 1.0091x over previous
//
#include <hip/hip_runtime.h>
#include <hip/hip_bf16.h>

typedef __bf16 bf16;
typedef __bf16 bf16x4 __attribute__((ext_vector_type(4)));
typedef __bf16 bf16x8 __attribute__((ext_vector_type(8)));
typedef float floatx4 __attribute__((ext_vector_type(4)));

#define Bb   2
#define Ss   2048
#define HID  2048
#define NH   16
#define HD   128
#define HG   8

typedef __attribute__((address_space(3))) unsigned int lds_u32;
typedef const __attribute__((address_space(1))) unsigned int gbl_u32;

__device__ __forceinline__ float b2f(bf16 h) {
    unsigned short u = __builtin_bit_cast(unsigned short, h);
    unsigned int x = ((unsigned int)u) << 16;
    return __builtin_bit_cast(float, x);
}
__device__ __forceinline__ bf16 f2b(float f) {
    __hip_bfloat16 t = __float2bfloat16(f);
    return __builtin_bit_cast(bf16, t);
}
__device__ __forceinline__ bf16x8 load8_f32(const float* p) {
    float4 u = *(const float4*)p;
    float4 v = *(const float4*)(p + 4);
    bf16x8 r;
    r[0] = f2b(u.x); r[1] = f2b(u.y); r[2] = f2b(u.z); r[3] = f2b(u.w);
    r[4] = f2b(v.x); r[5] = f2b(v.y); r[6] = f2b(v.z); r[7] = f2b(v.w);
    return r;
}
// async global->LDS, 16B per lane; lds base must be wave-uniform
__device__ __forceinline__ void stage16(const bf16* g, bf16* l) {
    __builtin_amdgcn_global_load_lds((gbl_u32*)g, (lds_u32*)l, 16, 0, 0);
}

// ===========================================================================
// PATH A kernels (ws >= 64 MiB)
// ===========================================================================

// merged f32->bf16 conversion for x (2.10M f4), w_qkv (3.15M f4), w_o (1.05M f4)
__global__ __launch_bounds__(256) void cvt_all(
    const float* __restrict__ x, const float* __restrict__ wq,
    const float* __restrict__ wo,
    bf16* __restrict__ xb, bf16* __restrict__ wqb, bf16* __restrict__ wob)
{
    int idx = blockIdx.x * 256 + threadIdx.x;
    int stride = gridDim.x * 256;
    for (int i = idx; i < 6291456; i += stride) {
        const float* in; bf16* out; int k;
        if (i < 2097152)      { in = x;  out = xb;  k = i; }
        else if (i < 5242880) { in = wq; out = wqb; k = i - 2097152; }
        else                  { in = wo; out = wob; k = i - 5242880; }
        float4 v = ((const float4*)in)[k];
        bf16x4 o; o[0] = f2b(v.x); o[1] = f2b(v.y); o[2] = f2b(v.z); o[3] = f2b(v.w);
        ((bf16x4*)out)[k] = o;
    }
}

// ---------------------------------------------------------------------------
// Single-dispatch QKV GEMM + RoPE + head-split, v3: BK=64 (unchanged from r9
// — bank conflicts 1.285e7 -> 2.6e5 measured, 813 TF, ~89% of the 2-phase
// structural ceiling carrying the RoPE epilogue).
// ---------------------------------------------------------------------------
__global__ __launch_bounds__(256) void qkv_gemm_rope(
    const bf16* __restrict__ xb, const bf16* __restrict__ wqb,
    const float* __restrict__ c0, const float* __restrict__ c1,
    bf16* __restrict__ q, bf16* __restrict__ k, bf16* __restrict__ vT)
{
    __shared__ __attribute__((aligned(16))) char smem[128 * 132 * 2];
    bf16* As = (bf16*)smem;                 // [128][64] = 16 KB (K-loop only)
    bf16* Bs = (bf16*)(smem + 16384);       // [128][64] = 16 KB (K-loop only)
    typedef bf16 (*tile_t)[132];
    tile_t tile = (tile_t)smem;             // [128][132] (epilogue overlay)

    bool c0cos = (c0[0] > 0.5f);
    const float* cosT = c0cos ? c0 : c1;
    const float* sinT = c0cos ? c1 : c0;

    int tid = threadIdx.x, lane = tid & 63, w = tid >> 6;
    int l15 = lane & 15, quad = lane >> 4;
    int m0 = blockIdx.x * 128, n0 = blockIdx.y * 128;
    int mw = (w >> 1) * 64, nw = (w & 1) * 64;

    // staging: wave w rows [w*32, w*32+32), 8 rows per 1KB issue.
    // source col pre-swizzled: lane covers LDS (row, c0=(lane&7)*8) and must
    // load global col c0 ^ 8*(row&7), row&7 = lane>>3.
    int srow = w * 32 + (lane >> 3);
    int scol = ((lane & 7) ^ (lane >> 3)) * 8;
    const bf16* ga = xb  + (size_t)(m0 + srow) * HID + scol;
    const bf16* gb = wqb + (size_t)(n0 + srow) * HID + scol;
    bf16* la = As + w * 2048;
    bf16* lb = Bs + w * 2048;

    int sw = (l15 & 7) * 8;                 // read-side swizzle (row&7 = l15&7)

    floatx4 acc[4][4] = {};
    for (int k0 = 0; k0 < HID; k0 += 64) {
#pragma unroll
        for (int i = 0; i < 4; i++) {
            stage16(ga + (size_t)(i * 8) * HID + k0, la + i * 512);
            stage16(gb + (size_t)(i * 8) * HID + k0, lb + i * 512);
        }
        __syncthreads();
#pragma unroll
        for (int ks = 0; ks < 2; ks++) {
            int cb = (ks * 32 + quad * 8) ^ sw;
            bf16x8 a[4], b[4];
#pragma unroll
            for (int i = 0; i < 4; i++) {
                a[i] = *(const bf16x8*)&As[(mw + i * 16 + l15) * 64 + cb];
                b[i] = *(const bf16x8*)&Bs[(nw + i * 16 + l15) * 64 + cb];
            }
#pragma unroll
            for (int i = 0; i < 4; i++)
#pragma unroll
                for (int j = 0; j < 4; j++)
                    acc[i][j] = __builtin_amdgcn_mfma_f32_16x16x32_bf16(a[i], b[j], acc[i][j], 0, 0, 0);
        }
        __syncthreads();
    }
    // after the final __syncthreads: no As/Bs readers remain, all DMAs
    // drained -> safe to overlay tile on the same LDS.

#pragma unroll
    for (int i = 0; i < 4; i++)
#pragma unroll
        for (int j = 0; j < 4; j++) {
            int row_l = mw + i * 16 + quad * 4;
            int col_l = nw + j * 16 + l15;
#pragma unroll
            for (int r = 0; r < 4; r++)
                tile[row_l + r][col_l] = f2b(acc[i][j][r]);
        }
    __syncthreads();

    int sec = blockIdx.y >> 4;
    int h   = blockIdx.y & 15;
    int bi  = m0 >> 11;
    int bh  = bi * NH + h;
    int sbase = m0 & (Ss - 1);

    if (sec == 2) {
        int d  = tid >> 1;
        int sh = (tid & 1) * 64;
        bf16* vrow = vT + ((size_t)bh * HD + d) * Ss + sbase + sh;
#pragma unroll 4
        for (int i = 0; i < 64; i += 4) {
            bf16x4 pk;
#pragma unroll
            for (int r = 0; r < 4; r++) pk[r] = tile[sh + i + r][d];
            *(bf16x4*)(vrow + i) = pk;
        }
    } else {
        bf16* dst = (sec == 0) ? q : k;
        int d  = tid & 63;
        int r0 = tid >> 6;
#pragma unroll 4
        for (int it = 0; it < 32; it++) {
            int row_l = it * 4 + r0;
            int s = sbase + row_l;
            float x1 = b2f(tile[row_l][d]);
            float x2 = b2f(tile[row_l][d + 64]);
            float cc1 = cosT[s * HD + d];
            float ss1 = sinT[s * HD + d];
            float cc2 = cosT[s * HD + d + 64];
            float ss2 = sinT[s * HD + d + 64];
            size_t o = ((size_t)bh * Ss + s) * HD + d;
            dst[o]      = f2b(x1 * cc1 - x2 * ss1);
            dst[o + 64] = f2b(x2 * cc2 + x1 * ss2);
        }
    }
}

// ---------------------------------------------------------------------------
// Full-grid causal flash attention (r4/r6 structure) + v8: constant-work CU
// pairing. Dispatch model: id&7 = XCD; id and id+256 land on the SAME CU
// (CU ~ (id&7, (id>>3)&31)). Old map gave CU c per-CU step-sums 104..160
// (slowest CU = +21% tail). New map: c=id&255, m=id>>8;
//   bh = (c&7)*4 + ((c>>3)&3)      (same 4-heads/XCD; same head for all 4
//                                   blocks resident on one CU -> L2/L1-hot K/V)
//   qt(m) = {31-c', 16+c', 15-c', c'}, c'=c>>5  -> per-CU qt-sum == 62,
//   step-sum == 132 for EVERY CU (ranges disjoint -> bijective).
// ---------------------------------------------------------------------------
#define ATTN_C1 (0.08838834764831845f * 1.44269504f)   /* scale * log2(e) */

#define STAGE_KV(BUF, KB)                                                        \
{                                                                                \
    const char* kg = kgbase + (size_t)(KB) * 256;                                \
    const char* vg = vgbase + (size_t)(KB) * 2;                                  \
    _Pragma("unroll")                                                            \
    for (int i = 0; i < 2; i++) {                                                \
        int P  = P0 + i * 1024;                                                  \
        int r  = P >> 8;                                                         \
        int cK = (P & 255) ^ ((r & 7) << 4);                                     \
        stage16((const bf16*)(kg + r * 256 + cK),                                \
                (bf16*)((char*)Kls[BUF] + wave * 2048 + i * 1024));              \
        int d  = P >> 6;                                                         \
        int cV = (P & 63) ^ (((d >> 1) & 3) << 4);                               \
        stage16((const bf16*)(vg + (size_t)d * 4096 + cV),                       \
                (bf16*)((char*)Vls[BUF] + wave * 2048 + i * 1024));              \
    }                                                                            \
}

__global__ __launch_bounds__(256, 4) void attn_full(
    const bf16* __restrict__ Q, const bf16* __restrict__ Kb, const bf16* __restrict__ VT,
    bf16* __restrict__ O)
{
    __shared__ __attribute__((aligned(16))) bf16 Kls[2][32 * 128];
    __shared__ __attribute__((aligned(16))) bf16 Vls[2][128 * 32];
    __shared__ bf16 pls[4][16][40];

    // constant-work CU pairing (see header comment)
    int id = blockIdx.x;
    int c  = id & 255;
    int mm = id >> 8;
    int bh = (c & 7) * 4 + ((c >> 3) & 3);
    int cp = c >> 5;                       // 0..7
    int qt;
    if      (mm == 0) qt = 31 - cp;
    else if (mm == 1) qt = 16 + cp;
    else if (mm == 2) qt = 15 - cp;
    else              qt = cp;

    int tid  = threadIdx.x;
    int wave = tid >> 6;
    int lane = tid & 63;
    int l15  = lane & 15;
    int quad = lane >> 4;

    int q0 = qt * 64 + wave * 16;
    int qg = q0 + l15;

    const char* kgbase = (const char*)(Kb + (size_t)bh * Ss * HD);
    const char* vgbase = (const char*)(VT + (size_t)bh * HD * Ss);
    int P0 = wave * 2048 + lane * 16;

    // stage tile 0 into buf 0 ASAP
    STAGE_KV(0, 0);

    const bf16* qptr = Q + ((size_t)bh * Ss + qg) * HD + quad * 8;
    bf16x8 qf[4];
#pragma unroll
    for (int s = 0; s < 4; s++) qf[s] = *(const bf16x8*)(qptr + s * 32);

    float m    = -1e30f;
    float bm   = 1.44269504e30f;   // = -m * log2(e); first step always rescales
    float lsum = 0.0f;             // per-lane partial; reduced in epilogue
    floatx4 ctx[8] = {};

    int nsteps = 2 * qt + 2;       // block-uniform trip count (wave 3's need)
    int buf = 0;
    __syncthreads();               // tile 0 ready (syncthreads drains vmcnt)

    for (int st = 0; st < nsteps; st++) {
        int kb = st * 32;
        if (st + 1 < nsteps) {
            int bufn = buf ^ 1;
            STAGE_KV(bufn, kb + 32);
        }
        if (kb <= q0 + 15) {
            bool masked = (kb + 31 > q0);   // wave-uniform
            const char* kls = (const char*)Kls[buf];
            const char* vls = (const char*)Vls[buf];

            floatx4 s0 = {0.f,0.f,0.f,0.f}, s1 = {0.f,0.f,0.f,0.f};
            __builtin_amdgcn_s_setprio(1);
#pragma unroll
            for (int s = 0; s < 4; s++) {
                int cc = (quad * 16 + s * 64) ^ ((l15 & 7) << 4);
                bf16x8 k0 = *(const bf16x8*)(kls + l15 * 256 + cc);
                bf16x8 k1 = *(const bf16x8*)(kls + (l15 + 16) * 256 + cc);
                s0 = __builtin_amdgcn_mfma_f32_16x16x32_bf16(k0, qf[s], s0, 0, 0, 0);
                s1 = __builtin_amdgcn_mfma_f32_16x16x32_bf16(k1, qf[s], s1, 0, 0, 0);
            }
            __builtin_amdgcn_s_setprio(0);

            float v0[4], v1[4];
#pragma unroll
            for (int r = 0; r < 4; r++) {
                int key0 = kb + quad * 4 + r;
                v0[r] = (masked && key0 > qg)      ? -1e9f : s0[r];
                v1[r] = (masked && key0 + 16 > qg) ? -1e9f : s1[r];
            }
            // per-lane local max -> wave-uniform defer check (no shuffles)
            float lmax = fmaxf(fmaxf(fmaxf(v0[0], v0[1]), fmaxf(v0[2], v0[3])),
                               fmaxf(fmaxf(v1[0], v1[1]), fmaxf(v1[2], v1[3])));
            if (!__all(lmax * 0.08838834764831845f <= m + 8.0f)) {
                float tm = lmax;
                tm = fmaxf(tm, __shfl_xor(tm, 16));
                tm = fmaxf(tm, __shfl_xor(tm, 32));
                float tms  = tm * 0.08838834764831845f;
                float mnew = fmaxf(m, tms);
                float bmn  = -mnew * 1.44269504f;
                float alpha = __builtin_exp2f(bmn - bm);
                m = mnew; bm = bmn;
                lsum *= alpha;
#pragma unroll
                for (int t = 0; t < 8; t++) {
                    ctx[t][0] *= alpha; ctx[t][1] *= alpha;
                    ctx[t][2] *= alpha; ctx[t][3] *= alpha;
                }
            }
            bf16x4 pk0, pk1; float ts = 0.f;
#pragma unroll
            for (int r = 0; r < 4; r++) {
                float pe0 = __builtin_exp2f(__builtin_fmaf(v0[r], ATTN_C1, bm));
                float pe1 = __builtin_exp2f(__builtin_fmaf(v1[r], ATTN_C1, bm));
                ts += pe0 + pe1;
                pk0[r] = f2b(pe0); pk1[r] = f2b(pe1);
            }
            lsum += ts;
            *(bf16x4*)&pls[wave][l15][quad * 4]      = pk0;
            *(bf16x4*)&pls[wave][l15][16 + quad * 4] = pk1;
            bf16x8 pf = *(const bf16x8*)&pls[wave][l15][quad * 8];

            __builtin_amdgcn_s_setprio(1);
#pragma unroll
            for (int t = 0; t < 8; t++) {
                int row = t * 16 + l15;
                bf16x8 vf = *(const bf16x8*)(vls + row * 64 +
                                             ((quad * 16) ^ (((row >> 1) & 3) << 4)));
                ctx[t] = __builtin_amdgcn_mfma_f32_16x16x32_bf16(vf, pf, ctx[t], 0, 0, 0);
            }
            __builtin_amdgcn_s_setprio(0);
        }
        __syncthreads();           // staged tile complete + all reads of buf done
        buf ^= 1;
    }

    // epilogue: cross-lane l reduction (once)
    lsum += __shfl_xor(lsum, 16);
    lsum += __shfl_xor(lsum, 32);
    float inv = 1.0f / lsum;

    int bi = bh >> 4, h = bh & (NH - 1);
    bf16* op = O + ((size_t)(bi * Ss + qg)) * HID + h * HD;
#pragma unroll
    for (int t = 0; t < 8; t++) {
        bf16x4 ov;
#pragma unroll
        for (int r = 0; r < 4; r++) ov[r] = f2b(ctx[t][r] * inv);
        *(bf16x4*)(op + t * 16 + quad * 4) = ov;
    }
}

// ---------------------------------------------------------------------------
// Out-projection v3 (unchanged from r9): 128x128 tile + BK=64 swizzled staging
// ---------------------------------------------------------------------------
__global__ __launch_bounds__(256) void out_gemm(
    const bf16* __restrict__ A, const bf16* __restrict__ B, float* __restrict__ C)
{
    __shared__ __attribute__((aligned(16))) bf16 As[128 * 64];
    __shared__ __attribute__((aligned(16))) bf16 Bs[128 * 64];

    int tid = threadIdx.x, lane = tid & 63, w = tid >> 6;
    int l15 = lane & 15, quad = lane >> 4;
    int m0 = blockIdx.x * 128, n0 = blockIdx.y * 128;
    int mw = (w >> 1) * 64, nw = (w & 1) * 64;

    int srow = w * 32 + (lane >> 3);
    int scol = ((lane & 7) ^ (lane >> 3)) * 8;
    const bf16* ga = A + (size_t)(m0 + srow) * HID + scol;
    const bf16* gb = B + (size_t)(n0 + srow) * HID + scol;
    bf16* la = As + w * 2048;
    bf16* lb = Bs + w * 2048;

    int sw = (l15 & 7) * 8;

    floatx4 acc[4][4] = {};
    for (int k0 = 0; k0 < HID; k0 += 64) {
#pragma unroll
        for (int i = 0; i < 4; i++) {
            stage16(ga + (size_t)(i * 8) * HID + k0, la + i * 512);
            stage16(gb + (size_t)(i * 8) * HID + k0, lb + i * 512);
        }
        __syncthreads();
#pragma unroll
        for (int ks = 0; ks < 2; ks++) {
            int cb = (ks * 32 + quad * 8) ^ sw;
            bf16x8 a[4], b[4];
#pragma unroll
            for (int i = 0; i < 4; i++) {
                a[i] = *(const bf16x8*)&As[(mw + i * 16 + l15) * 64 + cb];
                b[i] = *(const bf16x8*)&Bs[(nw + i * 16 + l15) * 64 + cb];
            }
#pragma unroll
            for (int i = 0; i < 4; i++)
#pragma unroll
                for (int j = 0; j < 4; j++)
                    acc[i][j] = __builtin_amdgcn_mfma_f32_16x16x32_bf16(a[i], b[j], acc[i][j], 0, 0, 0);
        }
        __syncthreads();
    }

#pragma unroll
    for (int i = 0; i < 4; i++)
#pragma unroll
        for (int j = 0; j < 4; j++) {
            int row = m0 + mw + i * 16 + quad * 4;
            int col = n0 + nw + j * 16 + l15;
#pragma unroll
            for (int r = 0; r < 4; r++)
                C[(size_t)(row + r) * HID + col] = acc[i][j][r];
        }
}

// ===========================================================================
// PATH B kernels (round-8 fallback, ws < 64 MiB) — proven passing
// ===========================================================================

__global__ __launch_bounds__(256) void qkv_rope_pass(
    const float* __restrict__ xb, const float* __restrict__ W,
    const float* __restrict__ c0, const float* __restrict__ c1,
    bf16* __restrict__ qc, bf16* __restrict__ kc, bf16* __restrict__ vc, int hg)
{
    __shared__ bf16 tile[128][132];
    bool c0cos = (c0[0] > 0.5f);
    const float* cosT = c0cos ? c0 : c1;
    const float* sinT = c0cos ? c1 : c0;

    int tid = threadIdx.x, lane = tid & 63, wave = tid >> 6;
    int l15 = lane & 15, quad = lane >> 4;
    int sec = blockIdx.y >> 3, hl = blockIdx.y & 7;
    int nbase = sec * (NH * HD) + (hg * HG + hl) * HD;
    int m0 = blockIdx.x * 128 + (wave >> 1) * 64;
    int n0l = (wave & 1) * 64;

    floatx4 acc[4][4] = {};
    const float* ap = xb + (size_t)(m0 + l15) * HID + quad * 8;
    const float* bp = W  + (size_t)(nbase + n0l + l15) * HID + quad * 8;
    for (int k0 = 0; k0 < HID; k0 += 32) {
        bf16x8 a[4], b[4];
#pragma unroll
        for (int i = 0; i < 4; i++) {
            a[i] = load8_f32(ap + (size_t)i * 16 * HID + k0);
            b[i] = load8_f32(bp + (size_t)i * 16 * HID + k0);
        }
#pragma unroll
        for (int i = 0; i < 4; i++)
#pragma unroll
            for (int j = 0; j < 4; j++)
                acc[i][j] = __builtin_amdgcn_mfma_f32_16x16x32_bf16(a[i], b[j], acc[i][j], 0, 0, 0);
    }
    int lr = (wave >> 1) * 64;
#pragma unroll
    for (int i = 0; i < 4; i++)
#pragma unroll
        for (int j = 0; j < 4; j++) {
            int row_l = lr + i * 16 + quad * 4;
            int col_l = n0l + j * 16 + l15;
#pragma unroll
            for (int r = 0; r < 4; r++)
                tile[row_l + r][col_l] = f2b(acc[i][j][r]);
        }
    __syncthreads();

    bf16* dst = (sec == 0) ? qc : (sec == 1) ? kc : vc;
    int d = tid & 63, r0 = tid >> 6;
#pragma unroll 4
    for (int it = 0; it < 32; it++) {
        int row_l = it * 4 + r0;
        int s = blockIdx.x * 128 + row_l;
        float x1 = b2f(tile[row_l][d]);
        float x2 = b2f(tile[row_l][d + 64]);
        size_t o = ((size_t)hl * Ss + s) * HD + d;
        if (sec == 2) { dst[o] = f2b(x1); dst[o + 64] = f2b(x2); }
        else {
            float cc1 = cosT[s * HD + d], ss1 = sinT[s * HD + d];
            float cc2 = cosT[s * HD + d + 64], ss2 = sinT[s * HD + d + 64];
            dst[o]      = f2b(x1 * cc1 - x2 * ss1);
            dst[o + 64] = f2b(x2 * cc2 + x1 * ss2);
        }
    }
}

__global__ __launch_bounds__(256) void attn_pass(
    const bf16* __restrict__ Q, const bf16* __restrict__ Kb, const bf16* __restrict__ Vb,
    bf16* __restrict__ Obase)
{
    __shared__ bf16 pls[4][16][40];
    int hl = blockIdx.x;
    int qt = (gridDim.y - 1) - blockIdx.y;
    int tid = threadIdx.x, wave = tid >> 6, lane = tid & 63;
    int l15 = lane & 15, quad = lane >> 4;
    int q0 = qt * 64 + wave * 16;
    int qg = q0 + l15;

    const bf16* qptr = Q + ((size_t)hl * Ss + qg) * HD + quad * 8;
    bf16x8 qf[4];
#pragma unroll
    for (int s = 0; s < 4; s++) qf[s] = *(const bf16x8*)(qptr + s * 32);

    float m = -1e30f, l = 0.0f;
    floatx4 ctx[8] = {};
    const float scale = 0.08838834764831845f;

    for (int kb = 0; kb <= q0 + 15; kb += 32) {
        floatx4 s0 = {0.f,0.f,0.f,0.f}, s1 = {0.f,0.f,0.f,0.f};
        const bf16* kp0 = Kb + ((size_t)hl * Ss + kb + l15) * HD + quad * 8;
        const bf16* kp1 = kp0 + (size_t)16 * HD;
#pragma unroll
        for (int s = 0; s < 4; s++) {
            bf16x8 k0 = *(const bf16x8*)(kp0 + s * 32);
            bf16x8 k1 = *(const bf16x8*)(kp1 + s * 32);
            s0 = __builtin_amdgcn_mfma_f32_16x16x32_bf16(k0, qf[s], s0, 0, 0, 0);
            s1 = __builtin_amdgcn_mfma_f32_16x16x32_bf16(k1, qf[s], s1, 0, 0, 0);
        }
        float v0[4], v1[4];
#pragma unroll
        for (int r = 0; r < 4; r++) {
            int key0 = kb + quad * 4 + r;
            v0[r] = (key0 > qg)      ? -1e9f : s0[r] * scale;
            v1[r] = (key0 + 16 > qg) ? -1e9f : s1[r] * scale;
        }
        float tmax = fmaxf(fmaxf(fmaxf(v0[0], v0[1]), fmaxf(v0[2], v0[3])),
                           fmaxf(fmaxf(v1[0], v1[1]), fmaxf(v1[2], v1[3])));
        tmax = fmaxf(tmax, __shfl_xor(tmax, 16));
        tmax = fmaxf(tmax, __shfl_xor(tmax, 32));
        float mnew = fmaxf(m, tmax);
        float alpha = __expf(m - mnew);
        float p0[4], p1[4], tsum = 0.0f;
#pragma unroll
        for (int r = 0; r < 4; r++) {
            p0[r] = __expf(v0[r] - mnew);
            p1[r] = __expf(v1[r] - mnew);
            tsum += p0[r] + p1[r];
        }
        tsum += __shfl_xor(tsum, 16);
        tsum += __shfl_xor(tsum, 32);
        l = l * alpha + tsum;
        m = mnew;
#pragma unroll
        for (int t = 0; t < 8; t++) {
            ctx[t][0] *= alpha; ctx[t][1] *= alpha;
            ctx[t][2] *= alpha; ctx[t][3] *= alpha;
        }
#pragma unroll
        for (int r = 0; r < 4; r++) {
            pls[wave][l15][quad * 4 + r]      = f2b(p0[r]);
            pls[wave][l15][16 + quad * 4 + r] = f2b(p1[r]);
        }
        bf16x8 pf = *(const bf16x8*)&pls[wave][l15][quad * 8];
        const short* vp = (const short*)(Vb + ((size_t)hl * Ss + kb) * HD);
#pragma unroll
        for (int t = 0; t < 8; t++) {
            bf16x8 vf;
#pragma unroll
            for (int j = 0; j < 8; j++) {
                short sv = vp[(size_t)(quad * 8 + j) * HD + t * 16 + l15];
                vf[j] = __builtin_bit_cast(bf16, sv);
            }
            ctx[t] = __builtin_amdgcn_mfma_f32_16x16x32_bf16(vf, pf, ctx[t], 0, 0, 0);
        }
    }
    float inv = 1.0f / l;
    bf16* op = Obase + (size_t)qg * HID + hl * HD;
#pragma unroll
    for (int t = 0; t < 8; t++) {
        bf16x4 ov;
#pragma unroll
        for (int r = 0; r < 4; r++) ov[r] = f2b(ctx[t][r] * inv);
        *(bf16x4*)(op + t * 16 + quad * 4) = ov;
    }
}

__global__ __launch_bounds__(256) void gemm_out_f32(
    const bf16* __restrict__ A, const float* __restrict__ B,
    float* __restrict__ C, int N, int K)
{
    int tid = threadIdx.x, lane = tid & 63, wave = tid >> 6;
    int l15 = lane & 15, quad = lane >> 4;
    int m0 = blockIdx.x * 128 + (wave >> 1) * 64;
    int n0 = blockIdx.y * 128 + (wave & 1) * 64;

    floatx4 acc[4][4] = {};
    const bf16*  ap = A + (size_t)(m0 + l15) * K + quad * 8;
    const float* bp = B + (size_t)(n0 + l15) * K + quad * 8;
    for (int k0 = 0; k0 < K; k0 += 32) {
        bf16x8 a[4], b[4];
#pragma unroll
        for (int i = 0; i < 4; i++) {
            a[i] = *(const bf16x8*)(ap + (size_t)i * 16 * K + k0);
            b[i] = load8_f32(bp + (size_t)i * 16 * K + k0);
        }
#pragma unroll
        for (int i = 0; i < 4; i++)
#pragma unroll
            for (int j = 0; j < 4; j++)
                acc[i][j] = __builtin_amdgcn_mfma_f32_16x16x32_bf16(a[i], b[j], acc[i][j], 0, 0, 0);
    }
#pragma unroll
    for (int i = 0; i < 4; i++)
#pragma unroll
        for (int j = 0; j < 4; j++) {
            int row = m0 + i * 16 + quad * 4;
            int col = n0 + j * 16 + l15;
#pragma unroll
            for (int r = 0; r < 4; r++)
                C[(size_t)(row + r) * N + col] = acc[i][j][r];
        }
}

extern "C" void kernel_launch(void* const* d_in, const int* in_sizes, int n_in,
                              void* d_out, int out_size, void* d_ws, size_t ws_size,
                              hipStream_t stream)
{
    const float *x = nullptr, *w_qkv = nullptr, *w_o = nullptr;
    const float *t0 = nullptr, *t1 = nullptr;
    for (int i = 0; i < n_in; i++) {
        const float* p = (const float*)d_in[i];
        if      (in_sizes[i] == 12582912) w_qkv = p;
        else if (in_sizes[i] ==  8388608) x     = p;
        else if (in_sizes[i] ==  4194304) w_o   = p;
        else if (in_sizes[i] ==   262144) { if (t0) t1 = p; else t0 = p; }
    }
    float* out = (float*)d_out;
    char* ws = (char*)d_ws;

    if (ws_size >= (size_t)67108864) {
        // ---------------- PATH A ----------------
        bf16* xb  = (bf16*)ws;                       // 16.78 MB
        bf16* wqb = (bf16*)(ws + 16777216);          // 25.17 MB
        bf16* wob = (bf16*)(ws + 41943040);          // 8.39 MB
        bf16* ctx = (bf16*)ws;                       // reuse xb after qkv
        bf16 *qb, *kbuf, *vT;
        if (ws_size >= (size_t)100663296) {          // A1: all in ws
            qb   = (bf16*)(ws + 50331648);
            kbuf = (bf16*)(ws + 67108864);
            vT   = (bf16*)(ws + 83886080);
        } else {                                     // A2: q,k in d_out scratch
            qb   = (bf16*)d_out;
            kbuf = (bf16*)((char*)d_out + 16777216);
            vT   = (bf16*)(ws + 50331648);
        }

        cvt_all<<<2048, 256, 0, stream>>>(x, w_qkv, w_o, xb, wqb, wob);

        qkv_gemm_rope<<<dim3(32, 48), 256, 0, stream>>>(xb, wqb, t0, t1, qb, kbuf, vT);
        attn_full<<<dim3(1024), 256, 0, stream>>>(qb, kbuf, vT, ctx);
        out_gemm<<<dim3(32, 16), 256, 0, stream>>>(ctx, wob, out);
    } else {
        // ---------------- PATH B (round-8 fallback) ----------------
        const size_t pe = (size_t)HG * Ss * HD;
        bf16* qc = (bf16*)d_ws;
        bf16* kc = qc + pe;
        bf16* vc = kc + pe;
        float* fin = (float*)d_ws;
        bf16* ctx = (bf16*)((char*)d_out + (size_t)16777216);

        for (int bi = 0; bi < Bb; bi++) {
            const float* xbp = x + (size_t)bi * Ss * HID;
            for (int hg = 0; hg < 2; hg++) {
                qkv_rope_pass<<<dim3(Ss / 128, 24), 256, 0, stream>>>(
                    xbp, w_qkv, t0, t1, qc, kc, vc, hg);
                bf16* Obase = ctx + (size_t)bi * Ss * HID + (size_t)hg * HG * HD;
                attn_pass<<<dim3(HG, Ss / 64), 256, 0, stream>>>(qc, kc, vc, Obase);
            }
        }
        gemm_out_f32<<<dim3(16, 16), 256, 0, stream>>>(ctx, w_o, fin, HID, HID);
        hipMemcpyAsync(out, fin, (size_t)2048 * HID * sizeof(float),
                       hipMemcpyDeviceToDevice, stream);
        gemm_out_f32<<<dim3(16, 16), 256, 0, stream>>>(ctx + (size_t)2048 * HID, w_o,
                                                       fin, HID, HID);
        hipMemcpyAsync(out + (size_t)2048 * HID, fin, (size_t)2048 * HID * sizeof(float),
                       hipMemcpyDeviceToDevice, stream);
    }
}

// Round 11
// 367.504 us; speedup vs baseline: 1.0961x; 1.0045x over previous
//
#include <hip/hip_runtime.h>
#include <hip/hip_bf16.h>

typedef __bf16 bf16;
typedef __bf16 bf16x4 __attribute__((ext_vector_type(4)));
typedef __bf16 bf16x8 __attribute__((ext_vector_type(8)));
typedef float floatx4 __attribute__((ext_vector_type(4)));

#define Bb   2
#define Ss   2048
#define HID  2048
#define NH   16
#define HD   128
#define HG   8

typedef __attribute__((address_space(3))) unsigned int lds_u32;
typedef const __attribute__((address_space(1))) unsigned int gbl_u32;

__device__ __forceinline__ float b2f(bf16 h) {
    unsigned short u = __builtin_bit_cast(unsigned short, h);
    unsigned int x = ((unsigned int)u) << 16;
    return __builtin_bit_cast(float, x);
}
__device__ __forceinline__ bf16 f2b(float f) {
    __hip_bfloat16 t = __float2bfloat16(f);
    return __builtin_bit_cast(bf16, t);
}
__device__ __forceinline__ bf16x8 load8_f32(const float* p) {
    float4 u = *(const float4*)p;
    float4 v = *(const float4*)(p + 4);
    bf16x8 r;
    r[0] = f2b(u.x); r[1] = f2b(u.y); r[2] = f2b(u.z); r[3] = f2b(u.w);
    r[4] = f2b(v.x); r[5] = f2b(v.y); r[6] = f2b(v.z); r[7] = f2b(v.w);
    return r;
}
// async global->LDS, 16B per lane; lds base must be wave-uniform
__device__ __forceinline__ void stage16(const bf16* g, bf16* l) {
    __builtin_amdgcn_global_load_lds((gbl_u32*)g, (lds_u32*)l, 16, 0, 0);
}

// ===========================================================================
// PATH A kernels (ws >= 64 MiB)
// ===========================================================================

// merged f32->bf16 conversion for x (2.10M f4), w_qkv (3.15M f4), w_o (1.05M f4)
__global__ __launch_bounds__(256) void cvt_all(
    const float* __restrict__ x, const float* __restrict__ wq,
    const float* __restrict__ wo,
    bf16* __restrict__ xb, bf16* __restrict__ wqb, bf16* __restrict__ wob)
{
    int idx = blockIdx.x * 256 + threadIdx.x;
    int stride = gridDim.x * 256;
    for (int i = idx; i < 6291456; i += stride) {
        const float* in; bf16* out; int k;
        if (i < 2097152)      { in = x;  out = xb;  k = i; }
        else if (i < 5242880) { in = wq; out = wqb; k = i - 2097152; }
        else                  { in = wo; out = wob; k = i - 5242880; }
        float4 v = ((const float4*)in)[k];
        bf16x4 o; o[0] = f2b(v.x); o[1] = f2b(v.y); o[2] = f2b(v.z); o[3] = f2b(v.w);
        ((bf16x4*)out)[k] = o;
    }
}

// ---------------------------------------------------------------------------
// Single-dispatch QKV GEMM + RoPE + head-split, v3: BK=64 (unchanged from r9
// — bank conflicts 1.285e7 -> 2.6e5 measured, 813 TF; frozen).
// ---------------------------------------------------------------------------
__global__ __launch_bounds__(256) void qkv_gemm_rope(
    const bf16* __restrict__ xb, const bf16* __restrict__ wqb,
    const float* __restrict__ c0, const float* __restrict__ c1,
    bf16* __restrict__ q, bf16* __restrict__ k, bf16* __restrict__ vT)
{
    __shared__ __attribute__((aligned(16))) char smem[128 * 132 * 2];
    bf16* As = (bf16*)smem;                 // [128][64] = 16 KB (K-loop only)
    bf16* Bs = (bf16*)(smem + 16384);       // [128][64] = 16 KB (K-loop only)
    typedef bf16 (*tile_t)[132];
    tile_t tile = (tile_t)smem;             // [128][132] (epilogue overlay)

    bool c0cos = (c0[0] > 0.5f);
    const float* cosT = c0cos ? c0 : c1;
    const float* sinT = c0cos ? c1 : c0;

    int tid = threadIdx.x, lane = tid & 63, w = tid >> 6;
    int l15 = lane & 15, quad = lane >> 4;
    int m0 = blockIdx.x * 128, n0 = blockIdx.y * 128;
    int mw = (w >> 1) * 64, nw = (w & 1) * 64;

    int srow = w * 32 + (lane >> 3);
    int scol = ((lane & 7) ^ (lane >> 3)) * 8;
    const bf16* ga = xb  + (size_t)(m0 + srow) * HID + scol;
    const bf16* gb = wqb + (size_t)(n0 + srow) * HID + scol;
    bf16* la = As + w * 2048;
    bf16* lb = Bs + w * 2048;

    int sw = (l15 & 7) * 8;                 // read-side swizzle (row&7 = l15&7)

    floatx4 acc[4][4] = {};
    for (int k0 = 0; k0 < HID; k0 += 64) {
#pragma unroll
        for (int i = 0; i < 4; i++) {
            stage16(ga + (size_t)(i * 8) * HID + k0, la + i * 512);
            stage16(gb + (size_t)(i * 8) * HID + k0, lb + i * 512);
        }
        __syncthreads();
#pragma unroll
        for (int ks = 0; ks < 2; ks++) {
            int cb = (ks * 32 + quad * 8) ^ sw;
            bf16x8 a[4], b[4];
#pragma unroll
            for (int i = 0; i < 4; i++) {
                a[i] = *(const bf16x8*)&As[(mw + i * 16 + l15) * 64 + cb];
                b[i] = *(const bf16x8*)&Bs[(nw + i * 16 + l15) * 64 + cb];
            }
#pragma unroll
            for (int i = 0; i < 4; i++)
#pragma unroll
                for (int j = 0; j < 4; j++)
                    acc[i][j] = __builtin_amdgcn_mfma_f32_16x16x32_bf16(a[i], b[j], acc[i][j], 0, 0, 0);
        }
        __syncthreads();
    }
    // after the final __syncthreads: no As/Bs readers remain, all DMAs
    // drained -> safe to overlay tile on the same LDS.

#pragma unroll
    for (int i = 0; i < 4; i++)
#pragma unroll
        for (int j = 0; j < 4; j++) {
            int row_l = mw + i * 16 + quad * 4;
            int col_l = nw + j * 16 + l15;
#pragma unroll
            for (int r = 0; r < 4; r++)
                tile[row_l + r][col_l] = f2b(acc[i][j][r]);
        }
    __syncthreads();

    int sec = blockIdx.y >> 4;
    int h   = blockIdx.y & 15;
    int bi  = m0 >> 11;
    int bh  = bi * NH + h;
    int sbase = m0 & (Ss - 1);

    if (sec == 2) {
        int d  = tid >> 1;
        int sh = (tid & 1) * 64;
        bf16* vrow = vT + ((size_t)bh * HD + d) * Ss + sbase + sh;
#pragma unroll 4
        for (int i = 0; i < 64; i += 4) {
            bf16x4 pk;
#pragma unroll
            for (int r = 0; r < 4; r++) pk[r] = tile[sh + i + r][d];
            *(bf16x4*)(vrow + i) = pk;
        }
    } else {
        bf16* dst = (sec == 0) ? q : k;
        int d  = tid & 63;
        int r0 = tid >> 6;
#pragma unroll 4
        for (int it = 0; it < 32; it++) {
            int row_l = it * 4 + r0;
            int s = sbase + row_l;
            float x1 = b2f(tile[row_l][d]);
            float x2 = b2f(tile[row_l][d + 64]);
            float cc1 = cosT[s * HD + d];
            float ss1 = sinT[s * HD + d];
            float cc2 = cosT[s * HD + d + 64];
            float ss2 = sinT[s * HD + d + 64];
            size_t o = ((size_t)bh * Ss + s) * HD + d;
            dst[o]      = f2b(x1 * cc1 - x2 * ss1);
            dst[o + 64] = f2b(x2 * cc2 + x1 * ss2);
        }
    }
}

// ---------------------------------------------------------------------------
// Full-grid causal flash attention (r10 version — frozen: LDS-shared K/V,
// constant-work CU pairing, ~92 us)
// ---------------------------------------------------------------------------
#define ATTN_C1 (0.08838834764831845f * 1.44269504f)   /* scale * log2(e) */

#define STAGE_KV(BUF, KB)                                                        \
{                                                                                \
    const char* kg = kgbase + (size_t)(KB) * 256;                                \
    const char* vg = vgbase + (size_t)(KB) * 2;                                  \
    _Pragma("unroll")                                                            \
    for (int i = 0; i < 2; i++) {                                                \
        int P  = P0 + i * 1024;                                                  \
        int r  = P >> 8;                                                         \
        int cK = (P & 255) ^ ((r & 7) << 4);                                     \
        stage16((const bf16*)(kg + r * 256 + cK),                                \
                (bf16*)((char*)Kls[BUF] + wave * 2048 + i * 1024));              \
        int d  = P >> 6;                                                         \
        int cV = (P & 63) ^ (((d >> 1) & 3) << 4);                               \
        stage16((const bf16*)(vg + (size_t)d * 4096 + cV),                       \
                (bf16*)((char*)Vls[BUF] + wave * 2048 + i * 1024));              \
    }                                                                            \
}

__global__ __launch_bounds__(256, 4) void attn_full(
    const bf16* __restrict__ Q, const bf16* __restrict__ Kb, const bf16* __restrict__ VT,
    bf16* __restrict__ O)
{
    __shared__ __attribute__((aligned(16))) bf16 Kls[2][32 * 128];
    __shared__ __attribute__((aligned(16))) bf16 Vls[2][128 * 32];
    __shared__ bf16 pls[4][16][40];

    // constant-work CU pairing: c=id&255 selects CU-slot, m=id>>8 the round;
    // bh = (c&7)*4 + ((c>>3)&3); qt(m) = {31-c',16+c',15-c',c'} -> per-CU
    // step-sum == 132 for every CU; bijective (qt quartile ranges disjoint).
    int id = blockIdx.x;
    int c  = id & 255;
    int mm = id >> 8;
    int bh = (c & 7) * 4 + ((c >> 3) & 3);
    int cp = c >> 5;
    int qt;
    if      (mm == 0) qt = 31 - cp;
    else if (mm == 1) qt = 16 + cp;
    else if (mm == 2) qt = 15 - cp;
    else              qt = cp;

    int tid  = threadIdx.x;
    int wave = tid >> 6;
    int lane = tid & 63;
    int l15  = lane & 15;
    int quad = lane >> 4;

    int q0 = qt * 64 + wave * 16;
    int qg = q0 + l15;

    const char* kgbase = (const char*)(Kb + (size_t)bh * Ss * HD);
    const char* vgbase = (const char*)(VT + (size_t)bh * HD * Ss);
    int P0 = wave * 2048 + lane * 16;

    // stage tile 0 into buf 0 ASAP
    STAGE_KV(0, 0);

    const bf16* qptr = Q + ((size_t)bh * Ss + qg) * HD + quad * 8;
    bf16x8 qf[4];
#pragma unroll
    for (int s = 0; s < 4; s++) qf[s] = *(const bf16x8*)(qptr + s * 32);

    float m    = -1e30f;
    float bm   = 1.44269504e30f;   // = -m * log2(e); first step always rescales
    float lsum = 0.0f;             // per-lane partial; reduced in epilogue
    floatx4 ctx[8] = {};

    int nsteps = 2 * qt + 2;       // block-uniform trip count (wave 3's need)
    int buf = 0;
    __syncthreads();               // tile 0 ready (syncthreads drains vmcnt)

    for (int st = 0; st < nsteps; st++) {
        int kb = st * 32;
        if (st + 1 < nsteps) {
            int bufn = buf ^ 1;
            STAGE_KV(bufn, kb + 32);
        }
        if (kb <= q0 + 15) {
            bool masked = (kb + 31 > q0);   // wave-uniform
            const char* kls = (const char*)Kls[buf];
            const char* vls = (const char*)Vls[buf];

            floatx4 s0 = {0.f,0.f,0.f,0.f}, s1 = {0.f,0.f,0.f,0.f};
            __builtin_amdgcn_s_setprio(1);
#pragma unroll
            for (int s = 0; s < 4; s++) {
                int cc = (quad * 16 + s * 64) ^ ((l15 & 7) << 4);
                bf16x8 k0 = *(const bf16x8*)(kls + l15 * 256 + cc);
                bf16x8 k1 = *(const bf16x8*)(kls + (l15 + 16) * 256 + cc);
                s0 = __builtin_amdgcn_mfma_f32_16x16x32_bf16(k0, qf[s], s0, 0, 0, 0);
                s1 = __builtin_amdgcn_mfma_f32_16x16x32_bf16(k1, qf[s], s1, 0, 0, 0);
            }
            __builtin_amdgcn_s_setprio(0);

            float v0[4], v1[4];
#pragma unroll
            for (int r = 0; r < 4; r++) {
                int key0 = kb + quad * 4 + r;
                v0[r] = (masked && key0 > qg)      ? -1e9f : s0[r];
                v1[r] = (masked && key0 + 16 > qg) ? -1e9f : s1[r];
            }
            // per-lane local max -> wave-uniform defer check (no shuffles)
            float lmax = fmaxf(fmaxf(fmaxf(v0[0], v0[1]), fmaxf(v0[2], v0[3])),
                               fmaxf(fmaxf(v1[0], v1[1]), fmaxf(v1[2], v1[3])));
            if (!__all(lmax * 0.08838834764831845f <= m + 8.0f)) {
                float tm = lmax;
                tm = fmaxf(tm, __shfl_xor(tm, 16));
                tm = fmaxf(tm, __shfl_xor(tm, 32));
                float tms  = tm * 0.08838834764831845f;
                float mnew = fmaxf(m, tms);
                float bmn  = -mnew * 1.44269504f;
                float alpha = __builtin_exp2f(bmn - bm);
                m = mnew; bm = bmn;
                lsum *= alpha;
#pragma unroll
                for (int t = 0; t < 8; t++) {
                    ctx[t][0] *= alpha; ctx[t][1] *= alpha;
                    ctx[t][2] *= alpha; ctx[t][3] *= alpha;
                }
            }
            bf16x4 pk0, pk1; float ts = 0.f;
#pragma unroll
            for (int r = 0; r < 4; r++) {
                float pe0 = __builtin_exp2f(__builtin_fmaf(v0[r], ATTN_C1, bm));
                float pe1 = __builtin_exp2f(__builtin_fmaf(v1[r], ATTN_C1, bm));
                ts += pe0 + pe1;
                pk0[r] = f2b(pe0); pk1[r] = f2b(pe1);
            }
            lsum += ts;
            *(bf16x4*)&pls[wave][l15][quad * 4]      = pk0;
            *(bf16x4*)&pls[wave][l15][16 + quad * 4] = pk1;
            bf16x8 pf = *(const bf16x8*)&pls[wave][l15][quad * 8];

            __builtin_amdgcn_s_setprio(1);
#pragma unroll
            for (int t = 0; t < 8; t++) {
                int row = t * 16 + l15;
                bf16x8 vf = *(const bf16x8*)(vls + row * 64 +
                                             ((quad * 16) ^ (((row >> 1) & 3) << 4)));
                ctx[t] = __builtin_amdgcn_mfma_f32_16x16x32_bf16(vf, pf, ctx[t], 0, 0, 0);
            }
            __builtin_amdgcn_s_setprio(0);
        }
        __syncthreads();           // staged tile complete + all reads of buf done
        buf ^= 1;
    }

    // epilogue: cross-lane l reduction (once)
    lsum += __shfl_xor(lsum, 16);
    lsum += __shfl_xor(lsum, 32);
    float inv = 1.0f / lsum;

    int bi = bh >> 4, h = bh & (NH - 1);
    bf16* op = O + ((size_t)(bi * Ss + qg)) * HID + h * HD;
#pragma unroll
    for (int t = 0; t < 8; t++) {
        bf16x4 ov;
#pragma unroll
        for (int r = 0; r < 4; r++) ov[r] = f2b(ctx[t][r] * inv);
        *(bf16x4*)(op + t * 16 + quad * 4) = ov;
    }
}

// ---------------------------------------------------------------------------
// Out-projection v4: 512-thread / 8-wave blocks, same 128x128 tile + BK=64
// swizzled staging. Old: 512 blocks x 4 waves = 8 waves/CU (half of qkv's
// TLP; barrier drain under-hidden). New: 2 blocks/CU x 8 waves = 16 waves/CU
// at UNCHANGED tile efficiency (r7 showed shrinking the tile is the wrong
// lever). Wave w: rows [(w>>2)*64, +64), cols [(w&3)*32, +32); acc[4][2]
// (~64 VGPR, no spill). Staging: wave w stages 16 rows of A and B (2 issues
// each), same pre-swizzled source pattern as qkv (row&7 = lane>>3).
// ---------------------------------------------------------------------------
__global__ __launch_bounds__(512) void out_gemm(
    const bf16* __restrict__ A, const bf16* __restrict__ B, float* __restrict__ C)
{
    __shared__ __attribute__((aligned(16))) bf16 As[128 * 64];
    __shared__ __attribute__((aligned(16))) bf16 Bs[128 * 64];

    int tid = threadIdx.x, lane = tid & 63, w = tid >> 6;   // w in 0..7
    int l15 = lane & 15, quad = lane >> 4;
    int m0 = blockIdx.x * 128, n0 = blockIdx.y * 128;
    int mw = (w >> 2) * 64;        // 2 wave-rows
    int nw = (w & 3) * 32;         // 4 wave-cols

    // staging: wave w covers rows [w*16, w*16+16) of A and B; 8 rows/issue.
    int srow = w * 16 + (lane >> 3);
    int scol = ((lane & 7) ^ (lane >> 3)) * 8;
    const bf16* ga = A + (size_t)(m0 + srow) * HID + scol;
    const bf16* gb = B + (size_t)(n0 + srow) * HID + scol;
    bf16* la = As + w * 1024;      // 16 rows * 64 cols
    bf16* lb = Bs + w * 1024;

    int sw = (l15 & 7) * 8;        // read-side swizzle (row&7 = l15&7)

    floatx4 acc[4][2] = {};
    for (int k0 = 0; k0 < HID; k0 += 64) {
#pragma unroll
        for (int i = 0; i < 2; i++) {
            stage16(ga + (size_t)(i * 8) * HID + k0, la + i * 512);
            stage16(gb + (size_t)(i * 8) * HID + k0, lb + i * 512);
        }
        __syncthreads();
#pragma unroll
        for (int ks = 0; ks < 2; ks++) {
            int cb = (ks * 32 + quad * 8) ^ sw;
            bf16x8 a[4], b[2];
#pragma unroll
            for (int i = 0; i < 4; i++)
                a[i] = *(const bf16x8*)&As[(mw + i * 16 + l15) * 64 + cb];
#pragma unroll
            for (int j = 0; j < 2; j++)
                b[j] = *(const bf16x8*)&Bs[(nw + j * 16 + l15) * 64 + cb];
#pragma unroll
            for (int i = 0; i < 4; i++)
#pragma unroll
                for (int j = 0; j < 2; j++)
                    acc[i][j] = __builtin_amdgcn_mfma_f32_16x16x32_bf16(a[i], b[j], acc[i][j], 0, 0, 0);
        }
        __syncthreads();
    }

#pragma unroll
    for (int i = 0; i < 4; i++)
#pragma unroll
        for (int j = 0; j < 2; j++) {
            int row = m0 + mw + i * 16 + quad * 4;
            int col = n0 + nw + j * 16 + l15;
#pragma unroll
            for (int r = 0; r < 4; r++)
                C[(size_t)(row + r) * HID + col] = acc[i][j][r];
        }
}

// ===========================================================================
// PATH B kernels (round-8 fallback, ws < 64 MiB) — proven passing
// ===========================================================================

__global__ __launch_bounds__(256) void qkv_rope_pass(
    const float* __restrict__ xb, const float* __restrict__ W,
    const float* __restrict__ c0, const float* __restrict__ c1,
    bf16* __restrict__ qc, bf16* __restrict__ kc, bf16* __restrict__ vc, int hg)
{
    __shared__ bf16 tile[128][132];
    bool c0cos = (c0[0] > 0.5f);
    const float* cosT = c0cos ? c0 : c1;
    const float* sinT = c0cos ? c1 : c0;

    int tid = threadIdx.x, lane = tid & 63, wave = tid >> 6;
    int l15 = lane & 15, quad = lane >> 4;
    int sec = blockIdx.y >> 3, hl = blockIdx.y & 7;
    int nbase = sec * (NH * HD) + (hg * HG + hl) * HD;
    int m0 = blockIdx.x * 128 + (wave >> 1) * 64;
    int n0l = (wave & 1) * 64;

    floatx4 acc[4][4] = {};
    const float* ap = xb + (size_t)(m0 + l15) * HID + quad * 8;
    const float* bp = W  + (size_t)(nbase + n0l + l15) * HID + quad * 8;
    for (int k0 = 0; k0 < HID; k0 += 32) {
        bf16x8 a[4], b[4];
#pragma unroll
        for (int i = 0; i < 4; i++) {
            a[i] = load8_f32(ap + (size_t)i * 16 * HID + k0);
            b[i] = load8_f32(bp + (size_t)i * 16 * HID + k0);
        }
#pragma unroll
        for (int i = 0; i < 4; i++)
#pragma unroll
            for (int j = 0; j < 4; j++)
                acc[i][j] = __builtin_amdgcn_mfma_f32_16x16x32_bf16(a[i], b[j], acc[i][j], 0, 0, 0);
    }
    int lr = (wave >> 1) * 64;
#pragma unroll
    for (int i = 0; i < 4; i++)
#pragma unroll
        for (int j = 0; j < 4; j++) {
            int row_l = lr + i * 16 + quad * 4;
            int col_l = n0l + j * 16 + l15;
#pragma unroll
            for (int r = 0; r < 4; r++)
                tile[row_l + r][col_l] = f2b(acc[i][j][r]);
        }
    __syncthreads();

    bf16* dst = (sec == 0) ? qc : (sec == 1) ? kc : vc;
    int d = tid & 63, r0 = tid >> 6;
#pragma unroll 4
    for (int it = 0; it < 32; it++) {
        int row_l = it * 4 + r0;
        int s = blockIdx.x * 128 + row_l;
        float x1 = b2f(tile[row_l][d]);
        float x2 = b2f(tile[row_l][d + 64]);
        size_t o = ((size_t)hl * Ss + s) * HD + d;
        if (sec == 2) { dst[o] = f2b(x1); dst[o + 64] = f2b(x2); }
        else {
            float cc1 = cosT[s * HD + d], ss1 = sinT[s * HD + d];
            float cc2 = cosT[s * HD + d + 64], ss2 = sinT[s * HD + d + 64];
            dst[o]      = f2b(x1 * cc1 - x2 * ss1);
            dst[o + 64] = f2b(x2 * cc2 + x1 * ss2);
        }
    }
}

__global__ __launch_bounds__(256) void attn_pass(
    const bf16* __restrict__ Q, const bf16* __restrict__ Kb, const bf16* __restrict__ Vb,
    bf16* __restrict__ Obase)
{
    __shared__ bf16 pls[4][16][40];
    int hl = blockIdx.x;
    int qt = (gridDim.y - 1) - blockIdx.y;
    int tid = threadIdx.x, wave = tid >> 6, lane = tid & 63;
    int l15 = lane & 15, quad = lane >> 4;
    int q0 = qt * 64 + wave * 16;
    int qg = q0 + l15;

    const bf16* qptr = Q + ((size_t)hl * Ss + qg) * HD + quad * 8;
    bf16x8 qf[4];
#pragma unroll
    for (int s = 0; s < 4; s++) qf[s] = *(const bf16x8*)(qptr + s * 32);

    float m = -1e30f, l = 0.0f;
    floatx4 ctx[8] = {};
    const float scale = 0.08838834764831845f;

    for (int kb = 0; kb <= q0 + 15; kb += 32) {
        floatx4 s0 = {0.f,0.f,0.f,0.f}, s1 = {0.f,0.f,0.f,0.f};
        const bf16* kp0 = Kb + ((size_t)hl * Ss + kb + l15) * HD + quad * 8;
        const bf16* kp1 = kp0 + (size_t)16 * HD;
#pragma unroll
        for (int s = 0; s < 4; s++) {
            bf16x8 k0 = *(const bf16x8*)(kp0 + s * 32);
            bf16x8 k1 = *(const bf16x8*)(kp1 + s * 32);
            s0 = __builtin_amdgcn_mfma_f32_16x16x32_bf16(k0, qf[s], s0, 0, 0, 0);
            s1 = __builtin_amdgcn_mfma_f32_16x16x32_bf16(k1, qf[s], s1, 0, 0, 0);
        }
        float v0[4], v1[4];
#pragma unroll
        for (int r = 0; r < 4; r++) {
            int key0 = kb + quad * 4 + r;
            v0[r] = (key0 > qg)      ? -1e9f : s0[r] * scale;
            v1[r] = (key0 + 16 > qg) ? -1e9f : s1[r] * scale;
        }
        float tmax = fmaxf(fmaxf(fmaxf(v0[0], v0[1]), fmaxf(v0[2], v0[3])),
                           fmaxf(fmaxf(v1[0], v1[1]), fmaxf(v1[2], v1[3])));
        tmax = fmaxf(tmax, __shfl_xor(tmax, 16));
        tmax = fmaxf(tmax, __shfl_xor(tmax, 32));
        float mnew = fmaxf(m, tmax);
        float alpha = __expf(m - mnew);
        float p0[4], p1[4], tsum = 0.0f;
#pragma unroll
        for (int r = 0; r < 4; r++) {
            p0[r] = __expf(v0[r] - mnew);
            p1[r] = __expf(v1[r] - mnew);
            tsum += p0[r] + p1[r];
        }
        tsum += __shfl_xor(tsum, 16);
        tsum += __shfl_xor(tsum, 32);
        l = l * alpha + tsum;
        m = mnew;
#pragma unroll
        for (int t = 0; t < 8; t++) {
            ctx[t][0] *= alpha; ctx[t][1] *= alpha;
            ctx[t][2] *= alpha; ctx[t][3] *= alpha;
        }
#pragma unroll
        for (int r = 0; r < 4; r++) {
            pls[wave][l15][quad * 4 + r]      = f2b(p0[r]);
            pls[wave][l15][16 + quad * 4 + r] = f2b(p1[r]);
        }
        bf16x8 pf = *(const bf16x8*)&pls[wave][l15][quad * 8];
        const short* vp = (const short*)(Vb + ((size_t)hl * Ss + kb) * HD);
#pragma unroll
        for (int t = 0; t < 8; t++) {
            bf16x8 vf;
#pragma unroll
            for (int j = 0; j < 8; j++) {
                short sv = vp[(size_t)(quad * 8 + j) * HD + t * 16 + l15];
                vf[j] = __builtin_bit_cast(bf16, sv);
            }
            ctx[t] = __builtin_amdgcn_mfma_f32_16x16x32_bf16(vf, pf, ctx[t], 0, 0, 0);
        }
    }
    float inv = 1.0f / l;
    bf16* op = Obase + (size_t)qg * HID + hl * HD;
#pragma unroll
    for (int t = 0; t < 8; t++) {
        bf16x4 ov;
#pragma unroll
        for (int r = 0; r < 4; r++) ov[r] = f2b(ctx[t][r] * inv);
        *(bf16x4*)(op + t * 16 + quad * 4) = ov;
    }
}

__global__ __launch_bounds__(256) void gemm_out_f32(
    const bf16* __restrict__ A, const float* __restrict__ B,
    float* __restrict__ C, int N, int K)
{
    int tid = threadIdx.x, lane = tid & 63, wave = tid >> 6;
    int l15 = lane & 15, quad = lane >> 4;
    int m0 = blockIdx.x * 128 + (wave >> 1) * 64;
    int n0 = blockIdx.y * 128 + (wave & 1) * 64;

    floatx4 acc[4][4] = {};
    const bf16*  ap = A + (size_t)(m0 + l15) * K + quad * 8;
    const float* bp = B + (size_t)(n0 + l15) * K + quad * 8;
    for (int k0 = 0; k0 < K; k0 += 32) {
        bf16x8 a[4], b[4];
#pragma unroll
        for (int i = 0; i < 4; i++) {
            a[i] = *(const bf16x8*)(ap + (size_t)i * 16 * K + k0);
            b[i] = load8_f32(bp + (size_t)i * 16 * K + k0);
        }
#pragma unroll
        for (int i = 0; i < 4; i++)
#pragma unroll
            for (int j = 0; j < 4; j++)
                acc[i][j] = __builtin_amdgcn_mfma_f32_16x16x32_bf16(a[i], b[j], acc[i][j], 0, 0, 0);
    }
#pragma unroll
    for (int i = 0; i < 4; i++)
#pragma unroll
        for (int j = 0; j < 4; j++) {
            int row = m0 + i * 16 + quad * 4;
            int col = n0 + j * 16 + l15;
#pragma unroll
            for (int r = 0; r < 4; r++)
                C[(size_t)(row + r) * N + col] = acc[i][j][r];
        }
}

extern "C" void kernel_launch(void* const* d_in, const int* in_sizes, int n_in,
                              void* d_out, int out_size, void* d_ws, size_t ws_size,
                              hipStream_t stream)
{
    const float *x = nullptr, *w_qkv = nullptr, *w_o = nullptr;
    const float *t0 = nullptr, *t1 = nullptr;
    for (int i = 0; i < n_in; i++) {
        const float* p = (const float*)d_in[i];
        if      (in_sizes[i] == 12582912) w_qkv = p;
        else if (in_sizes[i] ==  8388608) x     = p;
        else if (in_sizes[i] ==  4194304) w_o   = p;
        else if (in_sizes[i] ==   262144) { if (t0) t1 = p; else t0 = p; }
    }
    float* out = (float*)d_out;
    char* ws = (char*)d_ws;

    if (ws_size >= (size_t)67108864) {
        // ---------------- PATH A ----------------
        bf16* xb  = (bf16*)ws;                       // 16.78 MB
        bf16* wqb = (bf16*)(ws + 16777216);          // 25.17 MB
        bf16* wob = (bf16*)(ws + 41943040);          // 8.39 MB
        bf16* ctx = (bf16*)ws;                       // reuse xb after qkv
        bf16 *qb, *kbuf, *vT;
        if (ws_size >= (size_t)100663296) {          // A1: all in ws
            qb   = (bf16*)(ws + 50331648);
            kbuf = (bf16*)(ws + 67108864);
            vT   = (bf16*)(ws + 83886080);
        } else {                                     // A2: q,k in d_out scratch
            qb   = (bf16*)d_out;
            kbuf = (bf16*)((char*)d_out + 16777216);
            vT   = (bf16*)(ws + 50331648);
        }

        cvt_all<<<2048, 256, 0, stream>>>(x, w_qkv, w_o, xb, wqb, wob);

        qkv_gemm_rope<<<dim3(32, 48), 256, 0, stream>>>(xb, wqb, t0, t1, qb, kbuf, vT);
        attn_full<<<dim3(1024), 256, 0, stream>>>(qb, kbuf, vT, ctx);
        out_gemm<<<dim3(32, 16), 512, 0, stream>>>(ctx, wob, out);
    } else {
        // ---------------- PATH B (round-8 fallback) ----------------
        const size_t pe = (size_t)HG * Ss * HD;
        bf16* qc = (bf16*)d_ws;
        bf16* kc = qc + pe;
        bf16* vc = kc + pe;
        float* fin = (float*)d_ws;
        bf16* ctx = (bf16*)((char*)d_out + (size_t)16777216);

        for (int bi = 0; bi < Bb; bi++) {
            const float* xbp = x + (size_t)bi * Ss * HID;
            for (int hg = 0; hg < 2; hg++) {
                qkv_rope_pass<<<dim3(Ss / 128, 24), 256, 0, stream>>>(
                    xbp, w_qkv, t0, t1, qc, kc, vc, hg);
                bf16* Obase = ctx + (size_t)bi * Ss * HID + (size_t)hg * HG * HD;
                attn_pass<<<dim3(HG, Ss / 64), 256, 0, stream>>>(qc, kc, vc, Obase);
            }
        }
        gemm_out_f32<<<dim3(16, 16), 256, 0, stream>>>(ctx, w_o, fin, HID, HID);
        hipMemcpyAsync(out, fin, (size_t)2048 * HID * sizeof(float),
                       hipMemcpyDeviceToDevice, stream);
        gemm_out_f32<<<dim3(16, 16), 256, 0, stream>>>(ctx + (size_t)2048 * HID, w_o,
                                                       fin, HID, HID);
        hipMemcpyAsync(out + (size_t)2048 * HID, fin, (size_t)2048 * HID * sizeof(float),
                       hipMemcpyDeviceToDevice, stream);
    }
}